// Round 3
// baseline (2998.322 us; speedup 1.0000x reference)
//
#include <hip/hip_runtime.h>
#include <stdint.h>

// ============================================================================
// Encoder (6-layer rel-pos transformer), MI355X.
// R2: inputs/outputs are FLOAT32 (per reference); internals bf16 (harness
// compares in bf16 space, 2% threshold). R0/R1 NaN = f32 read as bf16.
// ws layout: 60.03 MiB, all-bf16 except f32 bias concat.
// ============================================================================

typedef unsigned short u16;
typedef __attribute__((ext_vector_type(8))) __bf16 bf16x8;
typedef __attribute__((ext_vector_type(4))) float f32x4;

#define B_ 8
#define T_ 768
#define C_ 512
#define F_ 2048

__device__ __forceinline__ float b2f(u16 u) {
    union { float f; uint32_t i; } x; x.i = ((uint32_t)u) << 16; return x.f;
}
__device__ __forceinline__ u16 f2b(float f) {
    union { float f; uint32_t i; } x; x.f = f;
    return (u16)((x.i + 0x7fffu + ((x.i >> 16) & 1u)) >> 16);  // RNE
}

// ---------------------------------------------------------------------------
// GEMM: out[M,N] = A[M,K] @ Bt[N,K]^T (+f32 bias, epilogue). TM=128 fixed.
// TN=128 -> 256 thr (2x2 waves), TN=64 -> 128 thr (2x1 waves); wave = 64x64.
// A/Bt/out are bf16 (u16). Batch via blockIdx.z: zb=z>>3, zh=z&7.
// EPI: 0 = +bias; 1 = relu(+bias); 3 = +bias then *epiScale on cols<512 (q).
// ---------------------------------------------------------------------------
template <int TN, int EPI>
__global__ __launch_bounds__(128 * (TN / 64)) void gemm_bt(
    const u16* __restrict__ A, long long aB1, long long aB2, int aStride,
    const u16* __restrict__ Bt, long long bB1, long long bB2, int bStride,
    const float* __restrict__ bias,
    u16* __restrict__ out, long long oB1, long long oB2, int oStride,
    int K, float epiScale)
{
    constexpr int WN = TN / 64;
    constexpr int NT = 128 * WN;
    const int tid = threadIdx.x;
    const int wave = tid >> 6, lane = tid & 63;
    const int wm = wave & 1, wn = wave >> 1;
    const int quad = lane >> 4, l16 = lane & 15;
    const int zb = blockIdx.z >> 3, zh = blockIdx.z & 7;
    A   += (long long)zb * aB1 + (long long)zh * aB2;
    Bt  += (long long)zb * bB1 + (long long)zh * bB2;
    out += (long long)zb * oB1 + (long long)zh * oB2;
    const int m0 = blockIdx.x * 128;
    const int n0 = blockIdx.y * TN;

    __shared__ u16 As[128 * 40];   // 32 k-elems + 8 pad per row
    __shared__ u16 Bs[TN * 40];

    const f32x4 vzero = {0.f, 0.f, 0.f, 0.f};
    f32x4 acc[4][4];
#pragma unroll
    for (int i = 0; i < 4; ++i)
#pragma unroll
        for (int j = 0; j < 4; ++j) acc[i][j] = vzero;

    for (int k0 = 0; k0 < K; k0 += 32) {
#pragma unroll
        for (int i = 0; i < 512 / NT; ++i) {   // A tile: 128 rows x 32
            int c = tid + i * NT;
            int row = c >> 2, kk = (c & 3) << 3;
            uint4 d = *(const uint4*)(A + (long long)(m0 + row) * aStride + (k0 + kk));
            *(uint4*)&As[row * 40 + kk] = d;
        }
#pragma unroll
        for (int i = 0; i < (TN * 4) / NT; ++i) {  // B tile: TN rows x 32
            int c = tid + i * NT;
            int row = c >> 2, kk = (c & 3) << 3;
            uint4 d = *(const uint4*)(Bt + (long long)(n0 + row) * bStride + (k0 + kk));
            *(uint4*)&Bs[row * 40 + kk] = d;
        }
        __syncthreads();
        bf16x8 af[4], bfr[4];
#pragma unroll
        for (int mi = 0; mi < 4; ++mi)
            af[mi] = *(const bf16x8*)&As[(wm * 64 + mi * 16 + l16) * 40 + quad * 8];
#pragma unroll
        for (int ni = 0; ni < 4; ++ni)
            bfr[ni] = *(const bf16x8*)&Bs[(wn * 64 + ni * 16 + l16) * 40 + quad * 8];
#pragma unroll
        for (int mi = 0; mi < 4; ++mi)
#pragma unroll
            for (int ni = 0; ni < 4; ++ni)
                acc[mi][ni] = __builtin_amdgcn_mfma_f32_16x16x32_bf16(
                    af[mi], bfr[ni], acc[mi][ni], 0, 0, 0);
        __syncthreads();
    }

    // C/D layout: col = lane&15, row = (lane>>4)*4 + reg  [m89/m91 verified]
#pragma unroll
    for (int mi = 0; mi < 4; ++mi) {
        int rowb = m0 + wm * 64 + mi * 16 + quad * 4;
#pragma unroll
        for (int ni = 0; ni < 4; ++ni) {
            int col = n0 + wn * 64 + ni * 16 + l16;
            float bv = bias ? bias[col] : 0.f;
#pragma unroll
            for (int r = 0; r < 4; ++r) {
                float v = acc[mi][ni][r] + bv;
                if (EPI == 1) v = v > 0.f ? v : 0.f;
                if (EPI == 3) { if (col < 512) v *= epiScale; }
                out[(long long)(rowb + r) * oStride + col] = f2b(v);
            }
        }
    }
}

// ---------------------------------------------------------------------------
// Transpose f32 src -> bf16 dst: dst[c][r] = (bf16)src[r][c]. Block (32,8).
// ---------------------------------------------------------------------------
__global__ void transpose_f2b(const float* __restrict__ src, int sStride,
                              u16* __restrict__ dst, int dStride)
{
    __shared__ u16 tile[32][33];
    const int r0 = blockIdx.y * 32, c0 = blockIdx.x * 32;
    const int tx = threadIdx.x, ty = threadIdx.y;
#pragma unroll
    for (int i = 0; i < 32; i += 8)
        tile[ty + i][tx] = f2b(src[(long long)(r0 + ty + i) * sStride + (c0 + tx)]);
    __syncthreads();
#pragma unroll
    for (int i = 0; i < 32; i += 8)
        dst[(long long)(c0 + ty + i) * dStride + (r0 + tx)] = tile[tx][ty + i];
}

// bf16 -> bf16 transpose with batch (z split zb=z>>3, zh=z&7).
__global__ void transpose_b(const u16* __restrict__ src, long long sB1, long long sB2, int sStride,
                            u16* __restrict__ dst, long long dB1, long long dB2, int dStride)
{
    __shared__ u16 tile[32][33];
    const int z = blockIdx.z, zb = z >> 3, zh = z & 7;
    src += (long long)zb * sB1 + (long long)zh * sB2;
    dst += (long long)zb * dB1 + (long long)zh * dB2;
    const int r0 = blockIdx.y * 32, c0 = blockIdx.x * 32;
    const int tx = threadIdx.x, ty = threadIdx.y;
#pragma unroll
    for (int i = 0; i < 32; i += 8)
        tile[ty + i][tx] = src[(long long)(r0 + ty + i) * sStride + (c0 + tx)];
    __syncthreads();
#pragma unroll
    for (int i = 0; i < 32; i += 8)
        dst[(long long)(c0 + ty + i) * dStride + (r0 + tx)] = tile[tx][ty + i];
}

// bqkv[l*1536 + n] = concat(bq, bk, bv) per layer (all f32)
__global__ void concat_bias(const float* __restrict__ bq, const float* __restrict__ bk,
                            const float* __restrict__ bv, float* __restrict__ dst)
{
    int i = blockIdx.x * 256 + threadIdx.x;   // 6*1536 = 9216
    int l = i / 1536, n = i - l * 1536;
    float v = (n < 512) ? bq[l * 512 + n]
             : (n < 1024 ? bk[l * 512 + (n - 512)] : bv[l * 512 + (n - 1024)]);
    dst[i] = v;
}

// xb[i] = bf16(x_f32[i] * mask_f32[i/512])
__global__ void mask_in(const float* __restrict__ x, const float* __restrict__ mask,
                        u16* __restrict__ out)
{
    int i = blockIdx.x * 256 + threadIdx.x;
    out[i] = f2b(x[i] * mask[i >> 9]);
}

// out_f32[i] = bf16val(xb[i]) * mask_f32[i/512]
__global__ void mask_out(const u16* __restrict__ x, const float* __restrict__ mask,
                         float* __restrict__ out)
{
    int i = blockIdx.x * 256 + threadIdx.x;
    out[i] = b2f(x[i]) * mask[i >> 9];
}

// ---------------------------------------------------------------------------
// Per-row: add rel-k band, mask, softmax. One wave per (bh, i) row of S.
// Grid: (T/4, NBH), block 256. q pre-scaled by 1/8 (so band term too).
// qkv/mask pointers pre-offset per batch-chunk; b here is LOCAL. erk f32.
// ---------------------------------------------------------------------------
__global__ __launch_bounds__(256) void softmax_band(
    u16* __restrict__ S, const u16* __restrict__ qkv, const float* __restrict__ mask,
    const float* __restrict__ erk)
{
    const int wave = threadIdx.x >> 6, lane = threadIdx.x & 63;
    const int i = blockIdx.x * 4 + wave;
    const int bh = blockIdx.y, b = bh >> 3, h = bh & 7;
    u16* row = S + ((long long)bh * T_ + i) * T_;
    const u16* qi = qkv + (long long)(b * T_ + i) * 1536 + h * 64;
    const float mi = mask[b * T_ + i];

    __shared__ float band[4][12];
    if (lane < 9) {
        const float* e = erk + lane * 64;
        float s = 0.f;
        for (int d = 0; d < 64; ++d) s += b2f(qi[d]) * e[d];
        band[wave][lane] = s;
    }
    __syncthreads();

    float v[12];
    float mx = -3.0e38f;
#pragma unroll
    for (int l = 0; l < 12; ++l) {
        int j = lane + l * 64;
        float s = b2f(row[j]);
        int d = j - i;
        if (d >= -4 && d <= 4) s += band[wave][d + 4];
        if (mi * mask[b * T_ + j] == 0.f) s = -10000.0f;
        v[l] = s;
        mx = fmaxf(mx, s);
    }
#pragma unroll
    for (int off = 32; off > 0; off >>= 1) mx = fmaxf(mx, __shfl_down(mx, off));
    mx = __shfl(mx, 0);
    float sum = 0.f;
#pragma unroll
    for (int l = 0; l < 12; ++l) { v[l] = __expf(v[l] - mx); sum += v[l]; }
#pragma unroll
    for (int off = 32; off > 0; off >>= 1) sum += __shfl_down(sum, off);
    sum = __shfl(sum, 0);
    const float r = 1.f / sum;
#pragma unroll
    for (int l = 0; l < 12; ++l) row[lane + l * 64] = f2b(v[l] * r);
}

// out[b,t,h*64+d] += sum_e P[bh,t,t+e-4] * erv[e][d]; one wave per (bh,t).
// P/outb pre-offset per chunk; bh local. erv f32. Grid.x = NBH*768/4.
__global__ __launch_bounds__(256) void band_v(
    const u16* __restrict__ P, const float* __restrict__ erv, u16* __restrict__ outb)
{
    const int wave = threadIdx.x >> 6, d = threadIdx.x & 63;
    const int rid = blockIdx.x * 4 + wave;
    const int bh = rid / T_, t = rid - bh * T_;
    const int b = bh >> 3, h = bh & 7;
    u16* o = outb + (long long)(b * T_ + t) * C_ + h * 64 + d;
    float acc = b2f(*o);
    const u16* prow = P + ((long long)bh * T_ + t) * T_;
#pragma unroll
    for (int e = 0; e < 9; ++e) {
        int j = t + e - 4;
        if (j >= 0 && j < T_) acc += b2f(prow[j]) * erv[e * 64 + d];
    }
    *o = f2b(acc);
}

// x = LayerNorm(x + y) * scale + bias; one wave per row of 512. sc/bi f32.
__global__ __launch_bounds__(256) void add_ln(
    const u16* __restrict__ x, const u16* __restrict__ y,
    const float* __restrict__ sc, const float* __restrict__ bi,
    u16* __restrict__ outx)
{
    const int wave = threadIdx.x >> 6, lane = threadIdx.x & 63;
    const long long r = (long long)blockIdx.x * 4 + wave;
    const u16* xr = x + r * C_;
    const u16* yr = y + r * C_;
    float v[8], s = 0.f;
#pragma unroll
    for (int l = 0; l < 8; ++l) {
        int c = lane + l * 64;
        v[l] = b2f(xr[c]) + b2f(yr[c]);
        s += v[l];
    }
#pragma unroll
    for (int off = 32; off > 0; off >>= 1) s += __shfl_down(s, off);
    s = __shfl(s, 0);
    const float mean = s * (1.f / 512.f);
    float var = 0.f;
#pragma unroll
    for (int l = 0; l < 8; ++l) { float d = v[l] - mean; var += d * d; }
#pragma unroll
    for (int off = 32; off > 0; off >>= 1) var += __shfl_down(var, off);
    var = __shfl(var, 0);
    const float rs = rsqrtf(var * (1.f / 512.f) + 1e-6f);
    u16* orow = outx + r * C_;
#pragma unroll
    for (int l = 0; l < 8; ++l) {
        int c = lane + l * 64;
        orow[c] = f2b((v[l] - mean) * rs * sc[c] + bi[c]);
    }
}

// ===========================================================================
extern "C" void kernel_launch(void* const* d_in, const int* in_sizes, int n_in,
                              void* d_out, int out_size, void* d_ws, size_t ws_size,
                              hipStream_t stream)
{
    const float* x    = (const float*)d_in[0];
    const float* mask = (const float*)d_in[1];
    const float* Wq   = (const float*)d_in[2];
    const float* bq   = (const float*)d_in[3];
    const float* Wk   = (const float*)d_in[4];
    const float* bk   = (const float*)d_in[5];
    const float* Wv   = (const float*)d_in[6];
    const float* bv   = (const float*)d_in[7];
    const float* Wo   = (const float*)d_in[8];
    const float* bo   = (const float*)d_in[9];
    const float* erk  = (const float*)d_in[10];
    const float* erv  = (const float*)d_in[11];
    const float* ln1s = (const float*)d_in[12];
    const float* ln1b = (const float*)d_in[13];
    const float* W1   = (const float*)d_in[14];
    const float* b1   = (const float*)d_in[15];
    const float* W2   = (const float*)d_in[16];
    const float* b2   = (const float*)d_in[17];
    const float* ln2s = (const float*)d_in[18];
    const float* ln2b = (const float*)d_in[19];
    float* out = (float*)d_out;
    u16* ws  = (u16*)d_ws;

    const long long CC = 512LL * 512, CF = 512LL * 2048, TT = 768LL * 768;
    const int M = B_ * T_;  // 6144

    // ws layout v3 (u16 units). Total 31,475,712 u16 = 60.03 MiB.
    u16* wqkvT   = ws;                     // [1536][512] bf16 (per-layer)
    u16* woT     = ws + 786432;            // [512][512]
    u16* w1T     = ws + 1048576;           // [2048][512]
    u16* w2T     = ws + 2097152;           // [512][2048]
    float* bqkv  = (float*)(ws + 3145728); // [6][1536] f32 (18432 u16)
    u16* xb      = ws + 3164160;           // [M][512]
    u16* qkvb    = ws + 6309888;           // [M][1536]
    u16* vtb     = ws + 15747072;          // [64][64][768]; aliased as yb
    u16* attnb   = ws + 18892800;          // [M][512]
    u16* scr     = ws + 22038528;          // 9,437,184: S [16][768][768] / h1 [3072][2048]
    u16* yb      = vtb;                    // alias: vtb dead after PV GEMM

    const dim3 tb(32, 8);

    concat_bias<<<36, 256, 0, stream>>>(bq, bk, bv, bqkv);
    mask_in<<<(M * 512) / 256, 256, 0, stream>>>(x, mask, xb);

    for (int l = 0; l < 6; ++l) {
        // --- per-layer weight transposes (f32 -> bf16, wT region reused) ---
        transpose_f2b<<<dim3(16, 16), tb, 0, stream>>>(Wq + (long long)l * CC, 512, wqkvT, 512);
        transpose_f2b<<<dim3(16, 16), tb, 0, stream>>>(Wk + (long long)l * CC, 512, wqkvT + 512 * 512, 512);
        transpose_f2b<<<dim3(16, 16), tb, 0, stream>>>(Wv + (long long)l * CC, 512, wqkvT + 1024 * 512, 512);
        transpose_f2b<<<dim3(16, 16), tb, 0, stream>>>(Wo + (long long)l * CC, 512, woT, 512);
        transpose_f2b<<<dim3(64, 16), tb, 0, stream>>>(W1 + (long long)l * CF, 2048, w1T, 512);
        transpose_f2b<<<dim3(16, 64), tb, 0, stream>>>(W2 + (long long)l * CF, 512,  w2T, 2048);

        // QKV fused: [6144,512] @ [1536,512]^T -> qkvb; q *= 1/8 in epilogue
        gemm_bt<128, 3><<<dim3(48, 12, 1), 256, 0, stream>>>(
            xb, 0, 0, 512, wqkvT, 0, 0, 512, bqkv + l * 1536,
            qkvb, 0, 0, 1536, 512, 0.125f);
        // V^T per head (all 64 bh): [64][768]
        transpose_b<<<dim3(2, 24, 64), tb, 0, stream>>>(
            qkvb + 1024, 768LL * 1536, 64, 1536,
            vtb, 8LL * 64 * 768, 64LL * 768, 768);

        // --- attention, chunked over 2 batches (16 bh) at a time ---
        for (int bg = 0; bg < 4; ++bg) {
            const long long qoff = (long long)bg * 2 * 768 * 1536;
            const long long aoff = (long long)bg * 2 * 768 * 512;
            // S = q @ k^T per (b,h)
            gemm_bt<128, 0><<<dim3(6, 6, 16), 256, 0, stream>>>(
                qkvb + qoff,       768LL * 1536, 64, 1536,
                qkvb + 512 + qoff, 768LL * 1536, 64, 1536,
                nullptr, scr, 8 * TT, TT, 768, 64, 0.f);
            // band rel-k + mask + softmax (in place)
            softmax_band<<<dim3(192, 16), 256, 0, stream>>>(
                scr, qkvb + qoff, mask + bg * 2 * 768, erk + l * 576);
            // out = P @ V per (b,h)
            gemm_bt<64, 0><<<dim3(6, 1, 16), 128, 0, stream>>>(
                scr, 8 * TT, TT, 768,
                vtb + (long long)bg * 2 * 8 * 64 * 768, 8LL * 64 * 768, 64LL * 768, 768,
                nullptr, attnb + aoff, 768LL * 512, 64, 512, 768, 0.f);
            // + band rel-v
            band_v<<<3072, 256, 0, stream>>>(scr, erv + l * 576, attnb + aoff);
        }

        // O projection -> yb (=vtb, dead now)
        gemm_bt<128, 0><<<dim3(48, 4, 1), 256, 0, stream>>>(
            attnb, 0, 0, 512, woT, 0, 0, 512, bo + l * 512,
            yb, 0, 0, 512, 512, 0.f);
        add_ln<<<1536, 256, 0, stream>>>(xb, yb, ln1s + l * 512, ln1b + l * 512, xb);

        // --- FFN, split in 2 row-halves so h1 fits in scr ---
        for (int hf = 0; hf < 2; ++hf) {
            const long long roff = (long long)hf * 3072;
            gemm_bt<128, 1><<<dim3(24, 16, 1), 256, 0, stream>>>(
                xb + roff * 512, 0, 0, 512, w1T, 0, 0, 512, b1 + l * 2048,
                scr, 0, 0, 2048, 512, 0.f);
            gemm_bt<128, 0><<<dim3(24, 4, 1), 256, 0, stream>>>(
                scr, 0, 0, 2048, w2T, 0, 0, 2048, b2 + l * 512,
                yb + roff * 512, 0, 0, 512, 2048, 0.f);
        }
        add_ln<<<1536, 256, 0, stream>>>(xb, yb, ln2s + l * 512, ln2b + l * 512, xb);
    }

    mask_out<<<(M * 512) / 256, 256, 0, stream>>>(xb, mask, out);
}

// Round 4
// 1864.903 us; speedup vs baseline: 1.6078x; 1.6078x over previous
//
#include <hip/hip_runtime.h>
#include <stdint.h>

// ============================================================================
// Encoder (6-layer rel-pos transformer), MI355X. f32 in/out, bf16 internals.
// R3: structural rework for occupancy/latency:
//  - BK=64 K-loop (half the barriers), XOR-swizzled LDS (<=2-way conflicts,
//    lane-contiguous for future global_load_lds), operand-swapped MFMA so the
//    epilogue stores ushort4 (8B/lane) instead of 64 scalar 2B stores.
//  - TN=64 tile variant for N=512 GEMMs (O-proj, FFN2): 384 blocks not 192.
//  - Unchunked attention + full-M FFN when ws_size allows (runtime branch,
//    deterministic per process); falls back to R2 chunking otherwise.
//  - Vectorized softmax / LN / mask kernels.
// ============================================================================

typedef unsigned short u16;
typedef __attribute__((ext_vector_type(8))) __bf16 bf16x8;
typedef __attribute__((ext_vector_type(4))) float f32x4;

#define B_ 8
#define T_ 768
#define C_ 512
#define F_ 2048

__device__ __forceinline__ float b2f(u16 u) {
    union { float f; uint32_t i; } x; x.i = ((uint32_t)u) << 16; return x.f;
}
__device__ __forceinline__ u16 f2b(float f) {
    union { float f; uint32_t i; } x; x.f = f;
    return (u16)((x.i + 0x7fffu + ((x.i >> 16) & 1u)) >> 16);  // RNE
}

// ---------------------------------------------------------------------------
// GEMM: out[M,N] = A[M,K] @ Bt[N,K]^T (+f32 bias, epilogue). TM=128, BK=64.
// TN=128 -> 256 thr (2x2 waves of 64x64), TN=64 -> 128 thr (2x1 waves).
// LDS: unpadded [row][64] with 16B-chunk XOR swizzle: phys chunk pc of row r
// holds logical chunk pc^(r&7). Staging thread c writes LDS linearly at c*16B.
// MFMA operand-swapped: lane l16 = output ROW, quad*4+reg = output COLS
// (consecutive) -> ushort4 packed stores.
// EPI: 0 = +bias; 1 = relu(+bias); 3 = +bias then *epiScale on cols<512 (q).
// ---------------------------------------------------------------------------
template <int TN, int EPI>
__global__ __launch_bounds__(128 * (TN / 64)) void gemm_bt(
    const u16* __restrict__ A, long long aB1, long long aB2, int aStride,
    const u16* __restrict__ Bt, long long bB1, long long bB2, int bStride,
    const float* __restrict__ bias,
    u16* __restrict__ out, long long oB1, long long oB2, int oStride,
    int K, float epiScale)
{
    constexpr int WN = TN / 64;
    constexpr int NT = 128 * WN;
    const int tid = threadIdx.x;
    const int wave = tid >> 6, lane = tid & 63;
    const int wm = wave & 1, wn = wave >> 1;
    const int quad = lane >> 4, l16 = lane & 15;
    const int zb = blockIdx.z >> 3, zh = blockIdx.z & 7;
    A   += (long long)zb * aB1 + (long long)zh * aB2;
    Bt  += (long long)zb * bB1 + (long long)zh * bB2;
    out += (long long)zb * oB1 + (long long)zh * oB2;
    const int m0 = blockIdx.x * 128;
    const int n0 = blockIdx.y * TN;

    __shared__ u16 As[128 * 64];
    __shared__ u16 Bs[TN * 64];

    const f32x4 vzero = {0.f, 0.f, 0.f, 0.f};
    f32x4 acc[4][4];
#pragma unroll
    for (int i = 0; i < 4; ++i)
#pragma unroll
        for (int j = 0; j < 4; ++j) acc[i][j] = vzero;

    for (int k0 = 0; k0 < K; k0 += 64) {
#pragma unroll
        for (int i = 0; i < 1024 / NT; ++i) {   // A tile: 128 rows x 8 chunks
            int c = tid + i * NT;
            int row = c >> 3, pc = c & 7, lc = pc ^ (row & 7);
            *(uint4*)&As[c * 8] =
                *(const uint4*)(A + (long long)(m0 + row) * aStride + (k0 + lc * 8));
        }
#pragma unroll
        for (int i = 0; i < (TN * 8) / NT; ++i) {  // B tile: TN rows x 8 chunks
            int c = tid + i * NT;
            int row = c >> 3, pc = c & 7, lc = pc ^ (row & 7);
            *(uint4*)&Bs[c * 8] =
                *(const uint4*)(Bt + (long long)(n0 + row) * bStride + (k0 + lc * 8));
        }
        __syncthreads();
#pragma unroll
        for (int ks = 0; ks < 2; ++ks) {
            bf16x8 af[4], bfr[4];
#pragma unroll
            for (int mi = 0; mi < 4; ++mi) {
                int row = wm * 64 + mi * 16 + l16;
                int pc = ((ks << 2) | quad) ^ (row & 7);
                af[mi] = *(const bf16x8*)&As[row * 64 + pc * 8];
            }
#pragma unroll
            for (int ni = 0; ni < 4; ++ni) {
                int row = wn * 64 + ni * 16 + l16;
                int pc = ((ks << 2) | quad) ^ (row & 7);
                bfr[ni] = *(const bf16x8*)&Bs[row * 64 + pc * 8];
            }
#pragma unroll
            for (int mi = 0; mi < 4; ++mi)
#pragma unroll
                for (int ni = 0; ni < 4; ++ni)
                    acc[mi][ni] = __builtin_amdgcn_mfma_f32_16x16x32_bf16(
                        bfr[ni], af[mi], acc[mi][ni], 0, 0, 0);  // swapped!
        }
        __syncthreads();
    }

    // Swapped-operand C/D: lane row m = l16 (+mi*16+wm*64), cols = quad*4+reg.
#pragma unroll
    for (int mi = 0; mi < 4; ++mi) {
        int row = m0 + wm * 64 + mi * 16 + l16;
#pragma unroll
        for (int ni = 0; ni < 4; ++ni) {
            int colb = n0 + wn * 64 + ni * 16 + quad * 4;
            u16 pk[4];
#pragma unroll
            for (int r = 0; r < 4; ++r) {
                float v = acc[mi][ni][r] + (bias ? bias[colb + r] : 0.f);
                if (EPI == 1) v = v > 0.f ? v : 0.f;
                if (EPI == 3) { if (colb + r < 512) v *= epiScale; }
                pk[r] = f2b(v);
            }
            uint2 p;
            p.x = (uint32_t)pk[0] | ((uint32_t)pk[1] << 16);
            p.y = (uint32_t)pk[2] | ((uint32_t)pk[3] << 16);
            *(uint2*)(out + (long long)row * oStride + colb) = p;
        }
    }
}

// ---------------------------------------------------------------------------
// Transpose f32 src -> bf16 dst (z selects one of up to 4 same-shape mats).
// ---------------------------------------------------------------------------
__global__ void transpose_f2b4(const float* __restrict__ s0, const float* __restrict__ s1,
                               const float* __restrict__ s2, const float* __restrict__ s3,
                               int sStride,
                               u16* __restrict__ d0, u16* __restrict__ d1,
                               u16* __restrict__ d2, u16* __restrict__ d3,
                               int dStride)
{
    __shared__ u16 tile[32][33];
    const int z = blockIdx.z;
    const float* src = z == 0 ? s0 : (z == 1 ? s1 : (z == 2 ? s2 : s3));
    u16* dst = z == 0 ? d0 : (z == 1 ? d1 : (z == 2 ? d2 : d3));
    const int r0 = blockIdx.y * 32, c0 = blockIdx.x * 32;
    const int tx = threadIdx.x, ty = threadIdx.y;
#pragma unroll
    for (int i = 0; i < 32; i += 8)
        tile[ty + i][tx] = f2b(src[(long long)(r0 + ty + i) * sStride + (c0 + tx)]);
    __syncthreads();
#pragma unroll
    for (int i = 0; i < 32; i += 8)
        dst[(long long)(c0 + ty + i) * dStride + (r0 + tx)] = tile[tx][ty + i];
}

__global__ void transpose_f2b(const float* __restrict__ src, int sStride,
                              u16* __restrict__ dst, int dStride)
{
    __shared__ u16 tile[32][33];
    const int r0 = blockIdx.y * 32, c0 = blockIdx.x * 32;
    const int tx = threadIdx.x, ty = threadIdx.y;
#pragma unroll
    for (int i = 0; i < 32; i += 8)
        tile[ty + i][tx] = f2b(src[(long long)(r0 + ty + i) * sStride + (c0 + tx)]);
    __syncthreads();
#pragma unroll
    for (int i = 0; i < 32; i += 8)
        dst[(long long)(c0 + ty + i) * dStride + (r0 + tx)] = tile[tx][ty + i];
}

// bf16 -> bf16 transpose with batch (z split zb=z>>3, zh=z&7).
__global__ void transpose_b(const u16* __restrict__ src, long long sB1, long long sB2, int sStride,
                            u16* __restrict__ dst, long long dB1, long long dB2, int dStride)
{
    __shared__ u16 tile[32][33];
    const int z = blockIdx.z, zb = z >> 3, zh = z & 7;
    src += (long long)zb * sB1 + (long long)zh * sB2;
    dst += (long long)zb * dB1 + (long long)zh * dB2;
    const int r0 = blockIdx.y * 32, c0 = blockIdx.x * 32;
    const int tx = threadIdx.x, ty = threadIdx.y;
#pragma unroll
    for (int i = 0; i < 32; i += 8)
        tile[ty + i][tx] = src[(long long)(r0 + ty + i) * sStride + (c0 + tx)];
    __syncthreads();
#pragma unroll
    for (int i = 0; i < 32; i += 8)
        dst[(long long)(c0 + ty + i) * dStride + (r0 + tx)] = tile[tx][ty + i];
}

// bqkv[l*1536 + n] = concat(bq, bk, bv) per layer (all f32)
__global__ void concat_bias(const float* __restrict__ bq, const float* __restrict__ bk,
                            const float* __restrict__ bv, float* __restrict__ dst)
{
    int i = blockIdx.x * 256 + threadIdx.x;   // 6*1536 = 9216
    int l = i / 1536, n = i - l * 1536;
    float v = (n < 512) ? bq[l * 512 + n]
             : (n < 1024 ? bk[l * 512 + (n - 512)] : bv[l * 512 + (n - 1024)]);
    dst[i] = v;
}

// xb[4i..] = bf16(x_f32 * mask_f32[row]); 4 elems/thread
__global__ void mask_in(const float* __restrict__ x, const float* __restrict__ mask,
                        u16* __restrict__ out)
{
    int i4 = (blockIdx.x * 256 + threadIdx.x) * 4;
    float4 xv = *(const float4*)(x + i4);
    float m = mask[i4 >> 9];
    u16 pk[4] = {f2b(xv.x * m), f2b(xv.y * m), f2b(xv.z * m), f2b(xv.w * m)};
    uint2 p; p.x = (uint32_t)pk[0] | ((uint32_t)pk[1] << 16);
    p.y = (uint32_t)pk[2] | ((uint32_t)pk[3] << 16);
    *(uint2*)(out + i4) = p;
}

// out_f32 = bf16val(xb) * mask_f32[row]; 4 elems/thread
__global__ void mask_out(const u16* __restrict__ x, const float* __restrict__ mask,
                         float* __restrict__ out)
{
    int i4 = (blockIdx.x * 256 + threadIdx.x) * 4;
    uint2 p = *(const uint2*)(x + i4);
    float m = mask[i4 >> 9];
    float4 o;
    o.x = b2f((u16)(p.x & 0xffff)) * m;
    o.y = b2f((u16)(p.x >> 16)) * m;
    o.z = b2f((u16)(p.y & 0xffff)) * m;
    o.w = b2f((u16)(p.y >> 16)) * m;
    *(float4*)(out + i4) = o;
}

// ---------------------------------------------------------------------------
// Per-row: add rel-k band, mask, softmax. One wave per (bh, i) row of S.
// Grid: (T/4, NBH), block 256. q pre-scaled by 1/8 (so band term too).
// qkv/mask pointers pre-offset per batch-chunk; b here is LOCAL. erk f32.
// ---------------------------------------------------------------------------
__global__ __launch_bounds__(256) void softmax_band(
    u16* __restrict__ S, const u16* __restrict__ qkv, const float* __restrict__ mask,
    const float* __restrict__ erk)
{
    const int wave = threadIdx.x >> 6, lane = threadIdx.x & 63;
    const int i = blockIdx.x * 4 + wave;
    const int bh = blockIdx.y, b = bh >> 3, h = bh & 7;
    u16* row = S + ((long long)bh * T_ + i) * T_;
    const u16* qi = qkv + (long long)(b * T_ + i) * 1536 + h * 64;
    const float mi = mask[b * T_ + i];

    __shared__ float band[4][12];
    if (lane < 9) {
        const float* e = erk + lane * 64;
        float s = 0.f;
        for (int d = 0; d < 64; ++d) s += b2f(qi[d]) * e[d];
        band[wave][lane] = s;
    }
    __syncthreads();

    float v[12];
    float mx = -3.0e38f;
#pragma unroll
    for (int it = 0; it < 3; ++it) {
        int chunk = it * 64 + lane;
        uint2 p = *(const uint2*)(row + chunk * 4);
        u16 e4[4] = {(u16)(p.x & 0xffff), (u16)(p.x >> 16),
                     (u16)(p.y & 0xffff), (u16)(p.y >> 16)};
#pragma unroll
        for (int e = 0; e < 4; ++e) {
            int j = chunk * 4 + e;
            float s = b2f(e4[e]);
            int d = j - i;
            if (d >= -4 && d <= 4) s += band[wave][d + 4];
            if (mi * mask[b * T_ + j] == 0.f) s = -10000.0f;
            v[it * 4 + e] = s;
            mx = fmaxf(mx, s);
        }
    }
#pragma unroll
    for (int off = 32; off > 0; off >>= 1) mx = fmaxf(mx, __shfl_down(mx, off));
    mx = __shfl(mx, 0);
    float sum = 0.f;
#pragma unroll
    for (int l = 0; l < 12; ++l) { v[l] = __expf(v[l] - mx); sum += v[l]; }
#pragma unroll
    for (int off = 32; off > 0; off >>= 1) sum += __shfl_down(sum, off);
    sum = __shfl(sum, 0);
    const float r = 1.f / sum;
#pragma unroll
    for (int it = 0; it < 3; ++it) {
        int chunk = it * 64 + lane;
        u16 pk[4];
#pragma unroll
        for (int e = 0; e < 4; ++e) pk[e] = f2b(v[it * 4 + e] * r);
        uint2 p; p.x = (uint32_t)pk[0] | ((uint32_t)pk[1] << 16);
        p.y = (uint32_t)pk[2] | ((uint32_t)pk[3] << 16);
        *(uint2*)(row + chunk * 4) = p;
    }
}

// out[b,t,h*64+d] += sum_e P[bh,t,t+e-4] * erv[e][d]; one wave per (bh,t).
// P/outb pre-offset per chunk; bh local. erv f32. Grid.x = NBH*768/4.
__global__ __launch_bounds__(256) void band_v(
    const u16* __restrict__ P, const float* __restrict__ erv, u16* __restrict__ outb)
{
    const int wave = threadIdx.x >> 6, d = threadIdx.x & 63;
    const int rid = blockIdx.x * 4 + wave;
    const int bh = rid / T_, t = rid - bh * T_;
    const int b = bh >> 3, h = bh & 7;
    u16* o = outb + (long long)(b * T_ + t) * C_ + h * 64 + d;
    float acc = b2f(*o);
    const u16* prow = P + ((long long)bh * T_ + t) * T_;
#pragma unroll
    for (int e = 0; e < 9; ++e) {
        int j = t + e - 4;
        if (j >= 0 && j < T_) acc += b2f(prow[j]) * erv[e * 64 + d];
    }
    *o = f2b(acc);
}

// x = LayerNorm(x + y) * scale + bias; one wave per row of 512. sc/bi f32.
__global__ __launch_bounds__(256) void add_ln(
    const u16* __restrict__ x, const u16* __restrict__ y,
    const float* __restrict__ sc, const float* __restrict__ bi,
    u16* __restrict__ outx)
{
    const int wave = threadIdx.x >> 6, lane = threadIdx.x & 63;
    const long long r = (long long)blockIdx.x * 4 + wave;
    const u16* xr = x + r * C_;
    const u16* yr = y + r * C_;
    float v[8], s = 0.f;
#pragma unroll
    for (int it = 0; it < 2; ++it) {
        int j0 = it * 256 + lane * 4;
        uint2 px = *(const uint2*)(xr + j0);
        uint2 py = *(const uint2*)(yr + j0);
        v[it * 4 + 0] = b2f((u16)(px.x & 0xffff)) + b2f((u16)(py.x & 0xffff));
        v[it * 4 + 1] = b2f((u16)(px.x >> 16))    + b2f((u16)(py.x >> 16));
        v[it * 4 + 2] = b2f((u16)(px.y & 0xffff)) + b2f((u16)(py.y & 0xffff));
        v[it * 4 + 3] = b2f((u16)(px.y >> 16))    + b2f((u16)(py.y >> 16));
        s += v[it * 4 + 0] + v[it * 4 + 1] + v[it * 4 + 2] + v[it * 4 + 3];
    }
#pragma unroll
    for (int off = 32; off > 0; off >>= 1) s += __shfl_down(s, off);
    s = __shfl(s, 0);
    const float mean = s * (1.f / 512.f);
    float var = 0.f;
#pragma unroll
    for (int l = 0; l < 8; ++l) { float d = v[l] - mean; var += d * d; }
#pragma unroll
    for (int off = 32; off > 0; off >>= 1) var += __shfl_down(var, off);
    var = __shfl(var, 0);
    const float rs = rsqrtf(var * (1.f / 512.f) + 1e-6f);
    u16* orow = outx + r * C_;
#pragma unroll
    for (int it = 0; it < 2; ++it) {
        int j0 = it * 256 + lane * 4;
        float4 s4 = *(const float4*)(sc + j0);
        float4 b4 = *(const float4*)(bi + j0);
        u16 pk[4];
        pk[0] = f2b((v[it * 4 + 0] - mean) * rs * s4.x + b4.x);
        pk[1] = f2b((v[it * 4 + 1] - mean) * rs * s4.y + b4.y);
        pk[2] = f2b((v[it * 4 + 2] - mean) * rs * s4.z + b4.z);
        pk[3] = f2b((v[it * 4 + 3] - mean) * rs * s4.w + b4.w);
        uint2 p; p.x = (uint32_t)pk[0] | ((uint32_t)pk[1] << 16);
        p.y = (uint32_t)pk[2] | ((uint32_t)pk[3] << 16);
        *(uint2*)(orow + j0) = p;
    }
}

// ===========================================================================
extern "C" void kernel_launch(void* const* d_in, const int* in_sizes, int n_in,
                              void* d_out, int out_size, void* d_ws, size_t ws_size,
                              hipStream_t stream)
{
    const float* x    = (const float*)d_in[0];
    const float* mask = (const float*)d_in[1];
    const float* Wq   = (const float*)d_in[2];
    const float* bq   = (const float*)d_in[3];
    const float* Wk   = (const float*)d_in[4];
    const float* bk   = (const float*)d_in[5];
    const float* Wv   = (const float*)d_in[6];
    const float* bv   = (const float*)d_in[7];
    const float* Wo   = (const float*)d_in[8];
    const float* bo   = (const float*)d_in[9];
    const float* erk  = (const float*)d_in[10];
    const float* erv  = (const float*)d_in[11];
    const float* ln1s = (const float*)d_in[12];
    const float* ln1b = (const float*)d_in[13];
    const float* W1   = (const float*)d_in[14];
    const float* b1   = (const float*)d_in[15];
    const float* W2   = (const float*)d_in[16];
    const float* b2   = (const float*)d_in[17];
    const float* ln2s = (const float*)d_in[18];
    const float* ln2b = (const float*)d_in[19];
    float* out = (float*)d_out;
    u16* ws  = (u16*)d_ws;

    const long long CC = 512LL * 512, CF = 512LL * 2048, TT = 768LL * 768;
    const int M = B_ * T_;  // 6144

    // ws layout (u16 units). Base = 22,038,528 u16; scr tail sized by mode.
    u16* wqkvT   = ws;                     // [1536][512] bf16 (per-layer)
    u16* woT     = ws + 786432;            // [512][512]
    u16* w1T     = ws + 1048576;           // [2048][512]
    u16* w2T     = ws + 2097152;           // [512][2048]
    float* bqkv  = (float*)(ws + 3145728); // [6][1536] f32 (18432 u16)
    u16* xb      = ws + 3164160;           // [M][512]
    u16* qkvb    = ws + 6309888;           // [M][1536]
    u16* vtb     = ws + 15747072;          // [64][64][768]; aliased as yb
    u16* attnb   = ws + 18892800;          // [M][512]
    u16* scr     = ws + 22038528;          // S groups / h1
    u16* yb      = vtb;                    // alias: vtb dead after PV GEMM

    // Full (unchunked) mode needs scr = 64*768*768 u16 -> total ~119.6 MB.
    const int big = (ws_size >= (size_t)(22038528 + 64LL * 768 * 768) * 2) ? 1 : 0;
    const int nG  = big ? 1 : 4;           // attention batch groups
    const int GB  = 8 / nG;                // batches per group
    const int SBH = GB * 8;                // bh per group
    const int nF  = big ? 1 : 2;           // FFN row halves
    const int FR  = M / nF;                // rows per FFN chunk

    const dim3 tb(32, 8);

    concat_bias<<<36, 256, 0, stream>>>(bq, bk, bv, bqkv);
    mask_in<<<(M * 512) / 1024, 256, 0, stream>>>(x, mask, xb);

    for (int l = 0; l < 6; ++l) {
        // --- per-layer weight transposes (f32 -> bf16, wT region reused) ---
        transpose_f2b4<<<dim3(16, 16, 4), tb, 0, stream>>>(
            Wq + (long long)l * CC, Wk + (long long)l * CC,
            Wv + (long long)l * CC, Wo + (long long)l * CC, 512,
            wqkvT, wqkvT + 512 * 512, wqkvT + 1024 * 512, woT, 512);
        transpose_f2b<<<dim3(64, 16), tb, 0, stream>>>(W1 + (long long)l * CF, 2048, w1T, 512);
        transpose_f2b<<<dim3(16, 64), tb, 0, stream>>>(W2 + (long long)l * CF, 512,  w2T, 2048);

        // QKV fused: [6144,512] @ [1536,512]^T -> qkvb; q *= 1/8 in epilogue
        gemm_bt<128, 3><<<dim3(48, 12, 1), 256, 0, stream>>>(
            xb, 0, 0, 512, wqkvT, 0, 0, 512, bqkv + l * 1536,
            qkvb, 0, 0, 1536, 512, 0.125f);
        // V^T per head (all 64 bh): [64][768]
        transpose_b<<<dim3(2, 24, 64), tb, 0, stream>>>(
            qkvb + 1024, 768LL * 1536, 64, 1536,
            vtb, 8LL * 64 * 768, 64LL * 768, 768);

        // --- attention over nG groups (1 group = whole batch when ws big) ---
        for (int bg = 0; bg < nG; ++bg) {
            const long long qoff = (long long)bg * GB * 768 * 1536;
            const long long aoff = (long long)bg * GB * 768 * 512;
            gemm_bt<128, 0><<<dim3(6, 6, SBH), 256, 0, stream>>>(
                qkvb + qoff,       768LL * 1536, 64, 1536,
                qkvb + 512 + qoff, 768LL * 1536, 64, 1536,
                nullptr, scr, 8 * TT, TT, 768, 64, 0.f);
            softmax_band<<<dim3(192, SBH), 256, 0, stream>>>(
                scr, qkvb + qoff, mask + bg * GB * 768, erk + l * 576);
            gemm_bt<64, 0><<<dim3(6, 1, SBH), 128, 0, stream>>>(
                scr, 8 * TT, TT, 768,
                vtb + (long long)bg * GB * 8 * 64 * 768, 8LL * 64 * 768, 64LL * 768, 768,
                nullptr, attnb + aoff, 768LL * 512, 64, 512, 768, 0.f);
            band_v<<<SBH * 192, 256, 0, stream>>>(scr, erv + l * 576, attnb + aoff);
        }

        // O projection -> yb (=vtb, dead now); TN=64 for 384 blocks
        gemm_bt<64, 0><<<dim3(48, 8, 1), 128, 0, stream>>>(
            attnb, 0, 0, 512, woT, 0, 0, 512, bo + l * 512,
            yb, 0, 0, 512, 512, 0.f);
        add_ln<<<1536, 256, 0, stream>>>(xb, yb, ln1s + l * 512, ln1b + l * 512, xb);

        // --- FFN (full-M when ws big) ---
        for (int hf = 0; hf < nF; ++hf) {
            const long long roff = (long long)hf * FR;
            gemm_bt<128, 1><<<dim3(FR / 128, 16, 1), 256, 0, stream>>>(
                xb + roff * 512, 0, 0, 512, w1T, 0, 0, 512, b1 + l * 2048,
                scr, 0, 0, 2048, 512, 0.f);
            gemm_bt<64, 0><<<dim3(FR / 128, 8, 1), 128, 0, stream>>>(
                scr, 0, 0, 2048, w2T, 0, 0, 2048, b2 + l * 512,
                yb + roff * 512, 0, 0, 512, 2048, 0.f);
        }
        add_ln<<<1536, 256, 0, stream>>>(xb, yb, ln2s + l * 512, ln2b + l * 512, xb);
    }

    mask_out<<<(M * 512) / 1024, 256, 0, stream>>>(xb, mask, out);
}

// Round 5
// 1403.997 us; speedup vs baseline: 2.1356x; 1.3283x over previous
//
#include <hip/hip_runtime.h>
#include <stdint.h>

// ============================================================================
// Encoder (6-layer rel-pos transformer), MI355X. f32 in/out, bf16 internals.
// R4: flash-fused attention — QK^T + band + mask + online softmax + PV +
// rel-v band in ONE kernel; S never hits HBM. Swapped-operand MFMA makes
// row-state per-lane (row = l16 for S and O). P converts C-layout->A-layout
// via wave-private XOR-swizzled LDS. Everything else unchanged from R3.
// ============================================================================

typedef unsigned short u16;
typedef __attribute__((ext_vector_type(8))) __bf16 bf16x8;
typedef __attribute__((ext_vector_type(4))) float f32x4;

#define B_ 8
#define T_ 768
#define C_ 512
#define F_ 2048

__device__ __forceinline__ float b2f(u16 u) {
    union { float f; uint32_t i; } x; x.i = ((uint32_t)u) << 16; return x.f;
}
__device__ __forceinline__ u16 f2b(float f) {
    union { float f; uint32_t i; } x; x.f = f;
    return (u16)((x.i + 0x7fffu + ((x.i >> 16) & 1u)) >> 16);  // RNE
}

// ---------------------------------------------------------------------------
// GEMM: out[M,N] = A[M,K] @ Bt[N,K]^T (+f32 bias, epilogue). TM=128, BK=64.
// Swapped-operand MFMA; XOR-swizzled LDS. (Unchanged from R3 — verified.)
// ---------------------------------------------------------------------------
template <int TN, int EPI>
__global__ __launch_bounds__(128 * (TN / 64)) void gemm_bt(
    const u16* __restrict__ A, long long aB1, long long aB2, int aStride,
    const u16* __restrict__ Bt, long long bB1, long long bB2, int bStride,
    const float* __restrict__ bias,
    u16* __restrict__ out, long long oB1, long long oB2, int oStride,
    int K, float epiScale)
{
    constexpr int WN = TN / 64;
    constexpr int NT = 128 * WN;
    const int tid = threadIdx.x;
    const int wave = tid >> 6, lane = tid & 63;
    const int wm = wave & 1, wn = wave >> 1;
    const int quad = lane >> 4, l16 = lane & 15;
    const int zb = blockIdx.z >> 3, zh = blockIdx.z & 7;
    A   += (long long)zb * aB1 + (long long)zh * aB2;
    Bt  += (long long)zb * bB1 + (long long)zh * bB2;
    out += (long long)zb * oB1 + (long long)zh * oB2;
    const int m0 = blockIdx.x * 128;
    const int n0 = blockIdx.y * TN;

    __shared__ u16 As[128 * 64];
    __shared__ u16 Bs[TN * 64];

    const f32x4 vzero = {0.f, 0.f, 0.f, 0.f};
    f32x4 acc[4][4];
#pragma unroll
    for (int i = 0; i < 4; ++i)
#pragma unroll
        for (int j = 0; j < 4; ++j) acc[i][j] = vzero;

    for (int k0 = 0; k0 < K; k0 += 64) {
#pragma unroll
        for (int i = 0; i < 1024 / NT; ++i) {
            int c = tid + i * NT;
            int row = c >> 3, pc = c & 7, lc = pc ^ (row & 7);
            *(uint4*)&As[c * 8] =
                *(const uint4*)(A + (long long)(m0 + row) * aStride + (k0 + lc * 8));
        }
#pragma unroll
        for (int i = 0; i < (TN * 8) / NT; ++i) {
            int c = tid + i * NT;
            int row = c >> 3, pc = c & 7, lc = pc ^ (row & 7);
            *(uint4*)&Bs[c * 8] =
                *(const uint4*)(Bt + (long long)(n0 + row) * bStride + (k0 + lc * 8));
        }
        __syncthreads();
#pragma unroll
        for (int ks = 0; ks < 2; ++ks) {
            bf16x8 af[4], bfr[4];
#pragma unroll
            for (int mi = 0; mi < 4; ++mi) {
                int row = wm * 64 + mi * 16 + l16;
                int pc = ((ks << 2) | quad) ^ (row & 7);
                af[mi] = *(const bf16x8*)&As[row * 64 + pc * 8];
            }
#pragma unroll
            for (int ni = 0; ni < 4; ++ni) {
                int row = wn * 64 + ni * 16 + l16;
                int pc = ((ks << 2) | quad) ^ (row & 7);
                bfr[ni] = *(const bf16x8*)&Bs[row * 64 + pc * 8];
            }
#pragma unroll
            for (int mi = 0; mi < 4; ++mi)
#pragma unroll
                for (int ni = 0; ni < 4; ++ni)
                    acc[mi][ni] = __builtin_amdgcn_mfma_f32_16x16x32_bf16(
                        bfr[ni], af[mi], acc[mi][ni], 0, 0, 0);
        }
        __syncthreads();
    }

#pragma unroll
    for (int mi = 0; mi < 4; ++mi) {
        int row = m0 + wm * 64 + mi * 16 + l16;
#pragma unroll
        for (int ni = 0; ni < 4; ++ni) {
            int colb = n0 + wn * 64 + ni * 16 + quad * 4;
            u16 pk[4];
#pragma unroll
            for (int r = 0; r < 4; ++r) {
                float v = acc[mi][ni][r] + (bias ? bias[colb + r] : 0.f);
                if (EPI == 1) v = v > 0.f ? v : 0.f;
                if (EPI == 3) { if (colb + r < 512) v *= epiScale; }
                pk[r] = f2b(v);
            }
            uint2 p;
            p.x = (uint32_t)pk[0] | ((uint32_t)pk[1] << 16);
            p.y = (uint32_t)pk[2] | ((uint32_t)pk[3] << 16);
            *(uint2*)(out + (long long)row * oStride + colb) = p;
        }
    }
}

// ---------------------------------------------------------------------------
// Flash attention: per block = one (b,h) and 64 q-rows. 4 waves, wave w owns
// q-rows [w*16, w*16+16). Online softmax; band rel-k inside; rel-v recomputed
// in epilogue. q in qkv is pre-scaled by 1/8.
// ---------------------------------------------------------------------------
__global__ __launch_bounds__(256) void flash_attn(
    const u16* __restrict__ qkv, const u16* __restrict__ vt,
    const float* __restrict__ mask,
    const float* __restrict__ erk, const float* __restrict__ erv,
    u16* __restrict__ outb)
{
    const int tid = threadIdx.x;
    const int w = tid >> 6, lane = tid & 63;
    const int quad = lane >> 4, l16 = lane & 15;
    const int qt = blockIdx.x, bh = blockIdx.y, b = bh >> 3, h = bh & 7;
    const int q0 = qt * 64;

    __shared__ u16 Ql[64 * 64];        // swizzled
    __shared__ u16 Kt[128 * 64];       // swizzled
    __shared__ u16 Vt[64 * 128];       // swizzled (rows = d)
    __shared__ u16 Pl[4][16 * 128];    // per-wave, swizzled by l16&7
    __shared__ float maskK[128];
    __shared__ float bandk[64][12];

    // Q tile: 64 rows x 8 chunks
#pragma unroll
    for (int i = 0; i < 2; ++i) {
        int c = tid + i * 256;
        int r = c >> 3, pc = c & 7, lc = pc ^ (r & 7);
        *(uint4*)&Ql[c * 8] =
            *(const uint4*)(qkv + (long long)(b * T_ + q0 + r) * 1536 + h * 64 + lc * 8);
    }
    // band_k precompute: bandk[r][e] = q~_r . erk_e  (from global, L1-hot)
    for (int idx = tid; idx < 576; idx += 256) {
        int r = idx / 9, e = idx - r * 9;
        const u16* qrow = qkv + (long long)(b * T_ + q0 + r) * 1536 + h * 64;
        const float* ee = erk + e * 64;
        float s = 0.f;
#pragma unroll 8
        for (int d = 0; d < 64; ++d) s += b2f(qrow[d]) * ee[d];
        bandk[r][e] = s;
    }

    const int i_row = q0 + w * 16 + l16;
    const float mi = mask[b * T_ + i_row];
    float m_run = -1e30f, l_run = 0.f;
    const f32x4 vzero = {0.f, 0.f, 0.f, 0.f};
    f32x4 vacc[4] = {vzero, vzero, vzero, vzero};

    __syncthreads();
    // preload q frags (row = w*16+l16)
    bf16x8 qf[2];
#pragma unroll
    for (int ks = 0; ks < 2; ++ks) {
        int r = w * 16 + l16;
        int pc = ((ks << 2) | quad) ^ (r & 7);
        qf[ks] = *(const bf16x8*)&Ql[r * 64 + pc * 8];
    }

    for (int kt = 0; kt < 6; ++kt) {
        __syncthreads();   // protect Kt/Vt/maskK from previous iteration use
#pragma unroll
        for (int i = 0; i < 4; ++i) {   // K tile: 128 rows x 8 chunks
            int c = tid + i * 256;
            int r = c >> 3, pc = c & 7, lc = pc ^ (r & 7);
            *(uint4*)&Kt[c * 8] =
                *(const uint4*)(qkv + (long long)(b * T_ + kt * 128 + r) * 1536 + 512 + h * 64 + lc * 8);
        }
#pragma unroll
        for (int i = 0; i < 4; ++i) {   // V^T tile: 64 rows(d) x 16 chunks
            int c = tid + i * 256;
            int r = c >> 4, pc = c & 15, lc = pc ^ (r & 7);
            *(uint4*)&Vt[c * 8] =
                *(const uint4*)(vt + ((long long)bh * 64 + r) * T_ + kt * 128 + lc * 8);
        }
        if (tid < 128) maskK[tid] = mask[b * T_ + kt * 128 + tid];
        __syncthreads();

        // S = Q @ K^T  (swapped: row = l16)
        f32x4 sacc[8];
#pragma unroll
        for (int ni = 0; ni < 8; ++ni) sacc[ni] = vzero;
#pragma unroll
        for (int ks = 0; ks < 2; ++ks)
#pragma unroll
            for (int ni = 0; ni < 8; ++ni) {
                int r = ni * 16 + l16;
                int pc = ((ks << 2) | quad) ^ (r & 7);
                bf16x8 kf = *(const bf16x8*)&Kt[r * 64 + pc * 8];
                sacc[ni] = __builtin_amdgcn_mfma_f32_16x16x32_bf16(kf, qf[ks], sacc[ni], 0, 0, 0);
            }

        // band + mask + row max (store adjusted s back into sacc)
        float mx = -1e30f;
#pragma unroll
        for (int ni = 0; ni < 8; ++ni)
#pragma unroll
            for (int r = 0; r < 4; ++r) {
                int jl = ni * 16 + quad * 4 + r;
                int j = kt * 128 + jl;
                float s = sacc[ni][r];
                int dlt = j - i_row;
                if (dlt >= -4 && dlt <= 4) s += bandk[w * 16 + l16][dlt + 4];
                if (mi * maskK[jl] == 0.f) s = -10000.0f;
                sacc[ni][r] = s;
                mx = fmaxf(mx, s);
            }
        mx = fmaxf(mx, __shfl_xor(mx, 16));
        mx = fmaxf(mx, __shfl_xor(mx, 32));
        float m_new = fmaxf(m_run, mx);
        float alpha = __expf(m_run - m_new);
        m_run = m_new;
        l_run *= alpha;
#pragma unroll
        for (int ni = 0; ni < 4; ++ni) vacc[ni] = vacc[ni] * alpha;

        // exp + write P (wave-private LDS, swizzled)
        float lsum = 0.f;
#pragma unroll
        for (int ni = 0; ni < 8; ++ni) {
            u16 pk[4];
#pragma unroll
            for (int r = 0; r < 4; ++r) {
                float u = __expf(sacc[ni][r] - m_new);
                lsum += u;
                pk[r] = f2b(u);
            }
            int c0 = ni * 16 + quad * 4;
            int lc = c0 >> 3, off = c0 & 7;
            int phys = ((lc ^ (l16 & 7)) << 3) + off;
            uint2 p;
            p.x = (uint32_t)pk[0] | ((uint32_t)pk[1] << 16);
            p.y = (uint32_t)pk[2] | ((uint32_t)pk[3] << 16);
            *(uint2*)&Pl[w][l16 * 128 + phys] = p;
        }
        l_run += lsum;

        // PV: vacc += P_tile @ V_tile   (row = l16, cols = d)
#pragma unroll
        for (int ks = 0; ks < 4; ++ks) {
            int pcc = ((ks << 2) | quad) ^ (l16 & 7);
            bf16x8 pf = *(const bf16x8*)&Pl[w][l16 * 128 + pcc * 8];
#pragma unroll
            for (int ni = 0; ni < 4; ++ni) {
                int r = ni * 16 + l16;
                int pc = ((ks << 2) | quad) ^ (r & 7);
                bf16x8 vf = *(const bf16x8*)&Vt[r * 128 + pc * 8];
                vacc[ni] = __builtin_amdgcn_mfma_f32_16x16x32_bf16(vf, pf, vacc[ni], 0, 0, 0);
            }
        }
    }

    // final l across quads
    l_run += __shfl_xor(l_run, 16);
    l_run += __shfl_xor(l_run, 32);
    const float rinv = 1.f / l_run;

    // rel-v band: p_band[e] = exp(q~_i.k_{i+e-4} + bandk - m)/l ; quads split e
    float pband[9];
#pragma unroll
    for (int e = 0; e < 9; ++e) pband[e] = 0.f;
    const u16* qrow = qkv + (long long)(b * T_ + i_row) * 1536 + h * 64;
#pragma unroll
    for (int k = 0; k < 3; ++k) {
        int e = quad * 3 + k;       // quads 0..2 cover e 0..8; quad 3 idle
        if (e < 9) {
            int j = i_row + e - 4;
            if (j >= 0 && j < T_) {
                const u16* krow = qkv + (long long)(b * T_ + j) * 1536 + 512 + h * 64;
                float s = 0.f;
#pragma unroll 8
                for (int d = 0; d < 64; ++d) s += b2f(qrow[d]) * b2f(krow[d]);
                s += bandk[w * 16 + l16][e];
                if (mi * mask[b * T_ + j] == 0.f) s = -10000.0f;
                pband[e] = __expf(s - m_run) * rinv;
            }
        }
    }
#pragma unroll
    for (int e = 0; e < 9; ++e) {
        pband[e] += __shfl_xor(pband[e], 16);
        pband[e] += __shfl_xor(pband[e], 32);
    }

    // epilogue: out = vacc/l + sum_e pband[e]*erv[e]
    u16* orow = outb + (long long)(b * T_ + i_row) * C_ + h * 64;
#pragma unroll
    for (int ni = 0; ni < 4; ++ni) {
        u16 pk[4];
#pragma unroll
        for (int r = 0; r < 4; ++r) {
            int d = ni * 16 + quad * 4 + r;
            float v = vacc[ni][r] * rinv;
#pragma unroll
            for (int e = 0; e < 9; ++e) v += pband[e] * erv[e * 64 + d];
            pk[r] = f2b(v);
        }
        uint2 p;
        p.x = (uint32_t)pk[0] | ((uint32_t)pk[1] << 16);
        p.y = (uint32_t)pk[2] | ((uint32_t)pk[3] << 16);
        *(uint2*)(orow + ni * 16 + quad * 4) = p;
    }
}

// ---------------------------------------------------------------------------
__global__ void transpose_f2b4(const float* __restrict__ s0, const float* __restrict__ s1,
                               const float* __restrict__ s2, const float* __restrict__ s3,
                               int sStride,
                               u16* __restrict__ d0, u16* __restrict__ d1,
                               u16* __restrict__ d2, u16* __restrict__ d3,
                               int dStride)
{
    __shared__ u16 tile[32][33];
    const int z = blockIdx.z;
    const float* src = z == 0 ? s0 : (z == 1 ? s1 : (z == 2 ? s2 : s3));
    u16* dst = z == 0 ? d0 : (z == 1 ? d1 : (z == 2 ? d2 : d3));
    const int r0 = blockIdx.y * 32, c0 = blockIdx.x * 32;
    const int tx = threadIdx.x, ty = threadIdx.y;
#pragma unroll
    for (int i = 0; i < 32; i += 8)
        tile[ty + i][tx] = f2b(src[(long long)(r0 + ty + i) * sStride + (c0 + tx)]);
    __syncthreads();
#pragma unroll
    for (int i = 0; i < 32; i += 8)
        dst[(long long)(c0 + ty + i) * dStride + (r0 + tx)] = tile[tx][ty + i];
}

__global__ void transpose_f2b(const float* __restrict__ src, int sStride,
                              u16* __restrict__ dst, int dStride)
{
    __shared__ u16 tile[32][33];
    const int r0 = blockIdx.y * 32, c0 = blockIdx.x * 32;
    const int tx = threadIdx.x, ty = threadIdx.y;
#pragma unroll
    for (int i = 0; i < 32; i += 8)
        tile[ty + i][tx] = f2b(src[(long long)(r0 + ty + i) * sStride + (c0 + tx)]);
    __syncthreads();
#pragma unroll
    for (int i = 0; i < 32; i += 8)
        dst[(long long)(c0 + ty + i) * dStride + (r0 + tx)] = tile[tx][ty + i];
}

__global__ void transpose_b(const u16* __restrict__ src, long long sB1, long long sB2, int sStride,
                            u16* __restrict__ dst, long long dB1, long long dB2, int dStride)
{
    __shared__ u16 tile[32][33];
    const int z = blockIdx.z, zb = z >> 3, zh = z & 7;
    src += (long long)zb * sB1 + (long long)zh * sB2;
    dst += (long long)zb * dB1 + (long long)zh * dB2;
    const int r0 = blockIdx.y * 32, c0 = blockIdx.x * 32;
    const int tx = threadIdx.x, ty = threadIdx.y;
#pragma unroll
    for (int i = 0; i < 32; i += 8)
        tile[ty + i][tx] = src[(long long)(r0 + ty + i) * sStride + (c0 + tx)];
    __syncthreads();
#pragma unroll
    for (int i = 0; i < 32; i += 8)
        dst[(long long)(c0 + ty + i) * dStride + (r0 + tx)] = tile[tx][ty + i];
}

__global__ void concat_bias(const float* __restrict__ bq, const float* __restrict__ bk,
                            const float* __restrict__ bv, float* __restrict__ dst)
{
    int i = blockIdx.x * 256 + threadIdx.x;
    int l = i / 1536, n = i - l * 1536;
    float v = (n < 512) ? bq[l * 512 + n]
             : (n < 1024 ? bk[l * 512 + (n - 512)] : bv[l * 512 + (n - 1024)]);
    dst[i] = v;
}

__global__ void mask_in(const float* __restrict__ x, const float* __restrict__ mask,
                        u16* __restrict__ out)
{
    int i4 = (blockIdx.x * 256 + threadIdx.x) * 4;
    float4 xv = *(const float4*)(x + i4);
    float m = mask[i4 >> 9];
    u16 pk[4] = {f2b(xv.x * m), f2b(xv.y * m), f2b(xv.z * m), f2b(xv.w * m)};
    uint2 p; p.x = (uint32_t)pk[0] | ((uint32_t)pk[1] << 16);
    p.y = (uint32_t)pk[2] | ((uint32_t)pk[3] << 16);
    *(uint2*)(out + i4) = p;
}

__global__ void mask_out(const u16* __restrict__ x, const float* __restrict__ mask,
                         float* __restrict__ out)
{
    int i4 = (blockIdx.x * 256 + threadIdx.x) * 4;
    uint2 p = *(const uint2*)(x + i4);
    float m = mask[i4 >> 9];
    float4 o;
    o.x = b2f((u16)(p.x & 0xffff)) * m;
    o.y = b2f((u16)(p.x >> 16)) * m;
    o.z = b2f((u16)(p.y & 0xffff)) * m;
    o.w = b2f((u16)(p.y >> 16)) * m;
    *(float4*)(out + i4) = o;
}

__global__ __launch_bounds__(256) void add_ln(
    const u16* __restrict__ x, const u16* __restrict__ y,
    const float* __restrict__ sc, const float* __restrict__ bi,
    u16* __restrict__ outx)
{
    const int wave = threadIdx.x >> 6, lane = threadIdx.x & 63;
    const long long r = (long long)blockIdx.x * 4 + wave;
    const u16* xr = x + r * C_;
    const u16* yr = y + r * C_;
    float v[8], s = 0.f;
#pragma unroll
    for (int it = 0; it < 2; ++it) {
        int j0 = it * 256 + lane * 4;
        uint2 px = *(const uint2*)(xr + j0);
        uint2 py = *(const uint2*)(yr + j0);
        v[it * 4 + 0] = b2f((u16)(px.x & 0xffff)) + b2f((u16)(py.x & 0xffff));
        v[it * 4 + 1] = b2f((u16)(px.x >> 16))    + b2f((u16)(py.x >> 16));
        v[it * 4 + 2] = b2f((u16)(px.y & 0xffff)) + b2f((u16)(py.y & 0xffff));
        v[it * 4 + 3] = b2f((u16)(px.y >> 16))    + b2f((u16)(py.y >> 16));
        s += v[it * 4 + 0] + v[it * 4 + 1] + v[it * 4 + 2] + v[it * 4 + 3];
    }
#pragma unroll
    for (int off = 32; off > 0; off >>= 1) s += __shfl_down(s, off);
    s = __shfl(s, 0);
    const float mean = s * (1.f / 512.f);
    float var = 0.f;
#pragma unroll
    for (int l = 0; l < 8; ++l) { float d = v[l] - mean; var += d * d; }
#pragma unroll
    for (int off = 32; off > 0; off >>= 1) var += __shfl_down(var, off);
    var = __shfl(var, 0);
    const float rs = rsqrtf(var * (1.f / 512.f) + 1e-6f);
    u16* orow = outx + r * C_;
#pragma unroll
    for (int it = 0; it < 2; ++it) {
        int j0 = it * 256 + lane * 4;
        float4 s4 = *(const float4*)(sc + j0);
        float4 b4 = *(const float4*)(bi + j0);
        u16 pk[4];
        pk[0] = f2b((v[it * 4 + 0] - mean) * rs * s4.x + b4.x);
        pk[1] = f2b((v[it * 4 + 1] - mean) * rs * s4.y + b4.y);
        pk[2] = f2b((v[it * 4 + 2] - mean) * rs * s4.z + b4.z);
        pk[3] = f2b((v[it * 4 + 3] - mean) * rs * s4.w + b4.w);
        uint2 p; p.x = (uint32_t)pk[0] | ((uint32_t)pk[1] << 16);
        p.y = (uint32_t)pk[2] | ((uint32_t)pk[3] << 16);
        *(uint2*)(orow + j0) = p;
    }
}

// ===========================================================================
extern "C" void kernel_launch(void* const* d_in, const int* in_sizes, int n_in,
                              void* d_out, int out_size, void* d_ws, size_t ws_size,
                              hipStream_t stream)
{
    const float* x    = (const float*)d_in[0];
    const float* mask = (const float*)d_in[1];
    const float* Wq   = (const float*)d_in[2];
    const float* bq   = (const float*)d_in[3];
    const float* Wk   = (const float*)d_in[4];
    const float* bk   = (const float*)d_in[5];
    const float* Wv   = (const float*)d_in[6];
    const float* bv   = (const float*)d_in[7];
    const float* Wo   = (const float*)d_in[8];
    const float* bo   = (const float*)d_in[9];
    const float* erk  = (const float*)d_in[10];
    const float* erv  = (const float*)d_in[11];
    const float* ln1s = (const float*)d_in[12];
    const float* ln1b = (const float*)d_in[13];
    const float* W1   = (const float*)d_in[14];
    const float* b1   = (const float*)d_in[15];
    const float* W2   = (const float*)d_in[16];
    const float* b2   = (const float*)d_in[17];
    const float* ln2s = (const float*)d_in[18];
    const float* ln2b = (const float*)d_in[19];
    float* out = (float*)d_out;
    u16* ws  = (u16*)d_ws;

    const long long CC = 512LL * 512, CF = 512LL * 2048;
    const int M = B_ * T_;  // 6144

    // ws layout (u16 units). Total 34,621,440 u16 = 66.0 MiB.
    u16* wqkvT   = ws;                     // [1536][512] bf16 (per-layer)
    u16* woT     = ws + 786432;            // [512][512]
    u16* w1T     = ws + 1048576;           // [2048][512]
    u16* w2T     = ws + 2097152;           // [512][2048]
    float* bqkv  = (float*)(ws + 3145728); // [6][1536] f32 (18432 u16)
    u16* xb      = ws + 3164160;           // [M][512]
    u16* qkvb    = ws + 6309888;           // [M][1536]
    u16* vtb     = ws + 15747072;          // [64][64][768]; aliased as yb
    u16* attnb   = ws + 18892800;          // [M][512]
    u16* scr     = ws + 22038528;          // h1 [M][2048] = 12,582,912 u16
    u16* yb      = vtb;                    // alias: vtb dead after flash_attn

    const dim3 tb(32, 8);

    concat_bias<<<36, 256, 0, stream>>>(bq, bk, bv, bqkv);
    mask_in<<<(M * 512) / 1024, 256, 0, stream>>>(x, mask, xb);

    for (int l = 0; l < 6; ++l) {
        transpose_f2b4<<<dim3(16, 16, 4), tb, 0, stream>>>(
            Wq + (long long)l * CC, Wk + (long long)l * CC,
            Wv + (long long)l * CC, Wo + (long long)l * CC, 512,
            wqkvT, wqkvT + 512 * 512, wqkvT + 1024 * 512, woT, 512);
        transpose_f2b<<<dim3(64, 16), tb, 0, stream>>>(W1 + (long long)l * CF, 2048, w1T, 512);
        transpose_f2b<<<dim3(16, 64), tb, 0, stream>>>(W2 + (long long)l * CF, 512,  w2T, 2048);

        // QKV: [6144,512] @ [1536,512]^T; q *= 1/8 in epilogue
        gemm_bt<128, 3><<<dim3(48, 12, 1), 256, 0, stream>>>(
            xb, 0, 0, 512, wqkvT, 0, 0, 512, bqkv + l * 1536,
            qkvb, 0, 0, 1536, 512, 0.125f);
        // V^T per head: [64][768]
        transpose_b<<<dim3(2, 24, 64), tb, 0, stream>>>(
            qkvb + 1024, 768LL * 1536, 64, 1536,
            vtb, 8LL * 64 * 768, 64LL * 768, 768);

        // fused attention -> attnb
        flash_attn<<<dim3(12, 64), 256, 0, stream>>>(
            qkvb, vtb, mask, erk + l * 576, erv + l * 576, attnb);

        // O projection -> yb (=vtb, dead now)
        gemm_bt<64, 0><<<dim3(48, 8, 1), 128, 0, stream>>>(
            attnb, 0, 0, 512, woT, 0, 0, 512, bo + l * 512,
            yb, 0, 0, 512, 512, 0.f);
        add_ln<<<1536, 256, 0, stream>>>(xb, yb, ln1s + l * 512, ln1b + l * 512, xb);

        // FFN
        gemm_bt<128, 1><<<dim3(48, 16, 1), 256, 0, stream>>>(
            xb, 0, 0, 512, w1T, 0, 0, 512, b1 + l * 2048,
            scr, 0, 0, 2048, 512, 0.f);
        gemm_bt<64, 0><<<dim3(48, 8, 1), 128, 0, stream>>>(
            scr, 0, 0, 2048, w2T, 0, 0, 2048, b2 + l * 512,
            yb, 0, 0, 512, 2048, 0.f);
        add_ln<<<1536, 256, 0, stream>>>(xb, yb, ln2s + l * 512, ln2b + l * 512, xb);
    }

    mask_out<<<(M * 512) / 1024, 256, 0, stream>>>(xb, mask, out);
}

// Round 6
// 1172.719 us; speedup vs baseline: 2.5567x; 1.1972x over previous
//
#include <hip/hip_runtime.h>
#include <stdint.h>

// ============================================================================
// Encoder (6-layer rel-pos transformer), MI355X. f32 in/out, bf16 internals.
// R5: flash_attn v2 — 64-wide k-tiles (LDS 34.8 KB -> 4 blocks/CU vs 2),
// bandk from precomputed global table (bandg_k kernel), rel-v band extracted
// from the P tile in LDS (no scalar global recompute). One-time weight
// transposes (ws_size proven >= 121.7 MB by R3's big-branch profile).
// ============================================================================

typedef unsigned short u16;
typedef __attribute__((ext_vector_type(8))) __bf16 bf16x8;
typedef __attribute__((ext_vector_type(4))) float f32x4;

#define B_ 8
#define T_ 768
#define C_ 512
#define F_ 2048

__device__ __forceinline__ float b2f(u16 u) {
    union { float f; uint32_t i; } x; x.i = ((uint32_t)u) << 16; return x.f;
}
__device__ __forceinline__ u16 f2b(float f) {
    union { float f; uint32_t i; } x; x.f = f;
    return (u16)((x.i + 0x7fffu + ((x.i >> 16) & 1u)) >> 16);  // RNE
}

// ---------------------------------------------------------------------------
// GEMM: out[M,N] = A[M,K] @ Bt[N,K]^T (+f32 bias, epilogue). TM=128, BK=64.
// Swapped-operand MFMA; XOR-swizzled LDS. (Unchanged from R3 — verified.)
// ---------------------------------------------------------------------------
template <int TN, int EPI>
__global__ __launch_bounds__(128 * (TN / 64)) void gemm_bt(
    const u16* __restrict__ A, long long aB1, long long aB2, int aStride,
    const u16* __restrict__ Bt, long long bB1, long long bB2, int bStride,
    const float* __restrict__ bias,
    u16* __restrict__ out, long long oB1, long long oB2, int oStride,
    int K, float epiScale)
{
    constexpr int WN = TN / 64;
    constexpr int NT = 128 * WN;
    const int tid = threadIdx.x;
    const int wave = tid >> 6, lane = tid & 63;
    const int wm = wave & 1, wn = wave >> 1;
    const int quad = lane >> 4, l16 = lane & 15;
    const int zb = blockIdx.z >> 3, zh = blockIdx.z & 7;
    A   += (long long)zb * aB1 + (long long)zh * aB2;
    Bt  += (long long)zb * bB1 + (long long)zh * bB2;
    out += (long long)zb * oB1 + (long long)zh * oB2;
    const int m0 = blockIdx.x * 128;
    const int n0 = blockIdx.y * TN;

    __shared__ u16 As[128 * 64];
    __shared__ u16 Bs[TN * 64];

    const f32x4 vzero = {0.f, 0.f, 0.f, 0.f};
    f32x4 acc[4][4];
#pragma unroll
    for (int i = 0; i < 4; ++i)
#pragma unroll
        for (int j = 0; j < 4; ++j) acc[i][j] = vzero;

    for (int k0 = 0; k0 < K; k0 += 64) {
#pragma unroll
        for (int i = 0; i < 1024 / NT; ++i) {
            int c = tid + i * NT;
            int row = c >> 3, pc = c & 7, lc = pc ^ (row & 7);
            *(uint4*)&As[c * 8] =
                *(const uint4*)(A + (long long)(m0 + row) * aStride + (k0 + lc * 8));
        }
#pragma unroll
        for (int i = 0; i < (TN * 8) / NT; ++i) {
            int c = tid + i * NT;
            int row = c >> 3, pc = c & 7, lc = pc ^ (row & 7);
            *(uint4*)&Bs[c * 8] =
                *(const uint4*)(Bt + (long long)(n0 + row) * bStride + (k0 + lc * 8));
        }
        __syncthreads();
#pragma unroll
        for (int ks = 0; ks < 2; ++ks) {
            bf16x8 af[4], bfr[4];
#pragma unroll
            for (int mi = 0; mi < 4; ++mi) {
                int row = wm * 64 + mi * 16 + l16;
                int pc = ((ks << 2) | quad) ^ (row & 7);
                af[mi] = *(const bf16x8*)&As[row * 64 + pc * 8];
            }
#pragma unroll
            for (int ni = 0; ni < 4; ++ni) {
                int row = wn * 64 + ni * 16 + l16;
                int pc = ((ks << 2) | quad) ^ (row & 7);
                bfr[ni] = *(const bf16x8*)&Bs[row * 64 + pc * 8];
            }
#pragma unroll
            for (int mi = 0; mi < 4; ++mi)
#pragma unroll
                for (int ni = 0; ni < 4; ++ni)
                    acc[mi][ni] = __builtin_amdgcn_mfma_f32_16x16x32_bf16(
                        bfr[ni], af[mi], acc[mi][ni], 0, 0, 0);
        }
        __syncthreads();
    }

#pragma unroll
    for (int mi = 0; mi < 4; ++mi) {
        int row = m0 + wm * 64 + mi * 16 + l16;
#pragma unroll
        for (int ni = 0; ni < 4; ++ni) {
            int colb = n0 + wn * 64 + ni * 16 + quad * 4;
            u16 pk[4];
#pragma unroll
            for (int r = 0; r < 4; ++r) {
                float v = acc[mi][ni][r] + (bias ? bias[colb + r] : 0.f);
                if (EPI == 1) v = v > 0.f ? v : 0.f;
                if (EPI == 3) { if (colb + r < 512) v *= epiScale; }
                pk[r] = f2b(v);
            }
            uint2 p;
            p.x = (uint32_t)pk[0] | ((uint32_t)pk[1] << 16);
            p.y = (uint32_t)pk[2] | ((uint32_t)pk[3] << 16);
            *(uint2*)(out + (long long)row * oStride + colb) = p;
        }
    }
}

// ---------------------------------------------------------------------------
// bandg[(t*8 + h)*9 + e] = q~[t,h,:] . erk[e,:]   (q pre-scaled by 1/8)
// One thread per (t,h). erk [9][64] f32 staged in LDS.
// ---------------------------------------------------------------------------
__global__ __launch_bounds__(256) void bandg_k(
    const u16* __restrict__ qkv, const float* __restrict__ erk,
    float* __restrict__ bandg)
{
    __shared__ float erkS[576];
    const int tid = threadIdx.x;
    for (int idx = tid; idx < 576; idx += 256) erkS[idx] = erk[idx];
    __syncthreads();
    const int gid = blockIdx.x * 256 + tid;       // 49152
    const int row = gid >> 3, h = gid & 7;
    const u16* q = qkv + (long long)row * 1536 + h * 64;
    float acc[9];
#pragma unroll
    for (int e = 0; e < 9; ++e) acc[e] = 0.f;
#pragma unroll
    for (int c = 0; c < 8; ++c) {
        uint4 d4 = *(const uint4*)(q + c * 8);
        const uint32_t dw[4] = {d4.x, d4.y, d4.z, d4.w};
#pragma unroll
        for (int j = 0; j < 8; ++j) {
            u16 uu = (u16)((dw[j >> 1] >> ((j & 1) * 16)) & 0xffff);
            float qv = b2f(uu);
            int d = c * 8 + j;
#pragma unroll
            for (int e = 0; e < 9; ++e) acc[e] += qv * erkS[e * 64 + d];
        }
    }
    float* o = bandg + (long long)gid * 9;
#pragma unroll
    for (int e = 0; e < 9; ++e) o[e] = acc[e];
}

// ---------------------------------------------------------------------------
// Flash attention v2: block = one (b,h) x 64 q-rows; k-tiles of 64 (12 iters).
// 4 waves; wave w owns q-rows [w*16, w*16+16). Online softmax per-lane
// (row = l16 via swapped MFMA). rel-k from bandg table; rel-v extracted from
// the P tile in LDS (alpha-rescaled across tiles). LDS ~34.8 KB.
// ---------------------------------------------------------------------------
__global__ __launch_bounds__(256) void flash_attn(
    const u16* __restrict__ qkv, const u16* __restrict__ vt,
    const float* __restrict__ mask, const float* __restrict__ bandg,
    const float* __restrict__ erv, u16* __restrict__ outb)
{
    const int tid = threadIdx.x;
    const int w = tid >> 6, lane = tid & 63;
    const int quad = lane >> 4, l16 = lane & 15;
    const int qt = blockIdx.x, bh = blockIdx.y, b = bh >> 3, h = bh & 7;
    const int q0 = qt * 64;

    __shared__ u16 Ql[64 * 64];
    __shared__ u16 Kt[64 * 64];
    __shared__ u16 Vt[64 * 64];
    __shared__ u16 Pl[4][16 * 64];
    __shared__ float bandk[64][10];
    __shared__ float maskK[64];

    // Q tile stage (512 16B chunks)
#pragma unroll
    for (int i = 0; i < 2; ++i) {
        int c = tid + i * 256;
        int r = c >> 3, pc = c & 7, lc = pc ^ (r & 7);
        *(uint4*)&Ql[c * 8] =
            *(const uint4*)(qkv + (long long)(b * T_ + q0 + r) * 1536 + h * 64 + lc * 8);
    }
    // bandk table load (precomputed)
    for (int idx = tid; idx < 576; idx += 256) {
        int r = idx / 9, e = idx - r * 9;
        bandk[r][e] = bandg[((long long)(b * T_ + q0 + r) * 8 + h) * 9 + e];
    }

    const int i_row = q0 + w * 16 + l16;
    const float mi = mask[b * T_ + i_row];
    float m_run = -1e30f, l_run = 0.f;
    const f32x4 vzero = {0.f, 0.f, 0.f, 0.f};
    f32x4 vacc[4] = {vzero, vzero, vzero, vzero};
    float pb[3] = {0.f, 0.f, 0.f};    // rel-v band accum, e = quad*3+k (quad<3)

    __syncthreads();
    bf16x8 qf[2];
#pragma unroll
    for (int ks = 0; ks < 2; ++ks) {
        int r = w * 16 + l16;
        int pc = ((ks << 2) | quad) ^ (r & 7);
        qf[ks] = *(const bf16x8*)&Ql[r * 64 + pc * 8];
    }

    for (int kt = 0; kt < 12; ++kt) {
        __syncthreads();
#pragma unroll
        for (int i = 0; i < 2; ++i) {   // K tile
            int c = tid + i * 256;
            int r = c >> 3, pc = c & 7, lc = pc ^ (r & 7);
            *(uint4*)&Kt[c * 8] =
                *(const uint4*)(qkv + (long long)(b * T_ + kt * 64 + r) * 1536 + 512 + h * 64 + lc * 8);
        }
#pragma unroll
        for (int i = 0; i < 2; ++i) {   // V^T tile (rows = d)
            int c = tid + i * 256;
            int r = c >> 3, pc = c & 7, lc = pc ^ (r & 7);
            *(uint4*)&Vt[c * 8] =
                *(const uint4*)(vt + ((long long)bh * 64 + r) * T_ + kt * 64 + lc * 8);
        }
        if (tid < 64) maskK[tid] = mask[b * T_ + kt * 64 + tid];
        __syncthreads();

        // S = Q @ K^T (row = l16)
        f32x4 sacc[4];
#pragma unroll
        for (int ni = 0; ni < 4; ++ni) sacc[ni] = vzero;
#pragma unroll
        for (int ks = 0; ks < 2; ++ks)
#pragma unroll
            for (int ni = 0; ni < 4; ++ni) {
                int r = ni * 16 + l16;
                int pc = ((ks << 2) | quad) ^ (r & 7);
                bf16x8 kf = *(const bf16x8*)&Kt[r * 64 + pc * 8];
                sacc[ni] = __builtin_amdgcn_mfma_f32_16x16x32_bf16(kf, qf[ks], sacc[ni], 0, 0, 0);
            }

        // band + mask + row max
        float mx = -1e30f;
#pragma unroll
        for (int ni = 0; ni < 4; ++ni)
#pragma unroll
            for (int r = 0; r < 4; ++r) {
                int jl = ni * 16 + quad * 4 + r;
                int j = kt * 64 + jl;
                float s = sacc[ni][r];
                int dlt = j - i_row;
                if (dlt >= -4 && dlt <= 4) s += bandk[w * 16 + l16][dlt + 4];
                if (mi * maskK[jl] == 0.f) s = -10000.0f;
                sacc[ni][r] = s;
                mx = fmaxf(mx, s);
            }
        mx = fmaxf(mx, __shfl_xor(mx, 16));
        mx = fmaxf(mx, __shfl_xor(mx, 32));
        float m_new = fmaxf(m_run, mx);
        float alpha = __expf(m_run - m_new);
        m_run = m_new;
        l_run *= alpha;
#pragma unroll
        for (int ni = 0; ni < 4; ++ni) vacc[ni] = vacc[ni] * alpha;
#pragma unroll
        for (int k = 0; k < 3; ++k) pb[k] *= alpha;

        // exp + write P tile (wave-private, swizzled by l16&7)
        float lsum = 0.f;
#pragma unroll
        for (int ni = 0; ni < 4; ++ni) {
            u16 pk[4];
#pragma unroll
            for (int r = 0; r < 4; ++r) {
                float u = __expf(sacc[ni][r] - m_new);
                lsum += u;
                pk[r] = f2b(u);
            }
            int c0 = ni * 16 + quad * 4;
            int phys = (((c0 >> 3) ^ (l16 & 7)) << 3) + (c0 & 7);
            uint2 p;
            p.x = (uint32_t)pk[0] | ((uint32_t)pk[1] << 16);
            p.y = (uint32_t)pk[2] | ((uint32_t)pk[3] << 16);
            *(uint2*)&Pl[w][l16 * 64 + phys] = p;
        }
        l_run += lsum;

        // rel-v band extraction from P tile: lane handles e = quad*3+k (quad<3)
#pragma unroll
        for (int k = 0; k < 3; ++k) {
            int e = quad * 3 + k;
            if (e < 9) {
                int jl = i_row + e - 4 - kt * 64;
                if (jl >= 0 && jl < 64) {
                    int phys = (((jl >> 3) ^ (l16 & 7)) << 3) + (jl & 7);
                    pb[k] += b2f(Pl[w][l16 * 64 + phys]);
                }
            }
        }

        // PV: vacc += P_tile @ V_tile (cols = d)
#pragma unroll
        for (int ks = 0; ks < 2; ++ks) {
            int pcc = ((ks << 2) | quad) ^ (l16 & 7);
            bf16x8 pf = *(const bf16x8*)&Pl[w][l16 * 64 + pcc * 8];
#pragma unroll
            for (int ni = 0; ni < 4; ++ni) {
                int r = ni * 16 + l16;
                int pc = ((ks << 2) | quad) ^ (r & 7);
                bf16x8 vf = *(const bf16x8*)&Vt[r * 64 + pc * 8];
                vacc[ni] = __builtin_amdgcn_mfma_f32_16x16x32_bf16(vf, pf, vacc[ni], 0, 0, 0);
            }
        }
    }

    l_run += __shfl_xor(l_run, 16);
    l_run += __shfl_xor(l_run, 32);
    const float rinv = 1.f / l_run;

    // combine pband across quads: e lives on quad e/3
    float pband[9];
#pragma unroll
    for (int e = 0; e < 9; ++e) {
        float val = (quad == e / 3) ? pb[e % 3] : 0.f;
        val += __shfl_xor(val, 16);
        val += __shfl_xor(val, 32);
        pband[e] = val * rinv;
    }

    // epilogue: out = vacc/l + sum_e pband[e]*erv[e]
    u16* orow = outb + (long long)(b * T_ + i_row) * C_ + h * 64;
#pragma unroll
    for (int ni = 0; ni < 4; ++ni) {
        u16 pk[4];
#pragma unroll
        for (int r = 0; r < 4; ++r) {
            int d = ni * 16 + quad * 4 + r;
            float v = vacc[ni][r] * rinv;
#pragma unroll
            for (int e = 0; e < 9; ++e) v += pband[e] * erv[e * 64 + d];
            pk[r] = f2b(v);
        }
        uint2 p;
        p.x = (uint32_t)pk[0] | ((uint32_t)pk[1] << 16);
        p.y = (uint32_t)pk[2] | ((uint32_t)pk[3] << 16);
        *(uint2*)(orow + ni * 16 + quad * 4) = p;
    }
}

// ---------------------------------------------------------------------------
// One-time weight transposes (f32 -> bf16), batched over layers.
// ---------------------------------------------------------------------------
__global__ void transpose_qkvo(const float* __restrict__ Wq, const float* __restrict__ Wk,
                               const float* __restrict__ Wv, const float* __restrict__ Wo,
                               u16* __restrict__ wqkvT, u16* __restrict__ woT)
{
    __shared__ u16 tile[32][33];
    const int z = blockIdx.z, l = z >> 2, which = z & 3;
    const float* src = (which == 0 ? Wq : which == 1 ? Wk : which == 2 ? Wv : Wo)
                       + (long long)l * 262144;
    u16* dst = (which == 3) ? woT + (long long)l * 262144
                            : wqkvT + (long long)l * 786432 + which * 262144;
    const int r0 = blockIdx.y * 32, c0 = blockIdx.x * 32;
    const int tx = threadIdx.x, ty = threadIdx.y;
#pragma unroll
    for (int i = 0; i < 32; i += 8)
        tile[ty + i][tx] = f2b(src[(long long)(r0 + ty + i) * 512 + (c0 + tx)]);
    __syncthreads();
#pragma unroll
    for (int i = 0; i < 32; i += 8)
        dst[(long long)(c0 + ty + i) * 512 + (r0 + tx)] = tile[tx][ty + i];
}

__global__ void transpose_f2bL(const float* __restrict__ src0, int sStride, long long sLayer,
                               u16* __restrict__ dst0, int dStride, long long dLayer)
{
    __shared__ u16 tile[32][33];
    const int l = blockIdx.z;
    const float* src = src0 + (long long)l * sLayer;
    u16* dst = dst0 + (long long)l * dLayer;
    const int r0 = blockIdx.y * 32, c0 = blockIdx.x * 32;
    const int tx = threadIdx.x, ty = threadIdx.y;
#pragma unroll
    for (int i = 0; i < 32; i += 8)
        tile[ty + i][tx] = f2b(src[(long long)(r0 + ty + i) * sStride + (c0 + tx)]);
    __syncthreads();
#pragma unroll
    for (int i = 0; i < 32; i += 8)
        dst[(long long)(c0 + ty + i) * dStride + (r0 + tx)] = tile[tx][ty + i];
}

__global__ void transpose_b(const u16* __restrict__ src, long long sB1, long long sB2, int sStride,
                            u16* __restrict__ dst, long long dB1, long long dB2, int dStride)
{
    __shared__ u16 tile[32][33];
    const int z = blockIdx.z, zb = z >> 3, zh = z & 7;
    src += (long long)zb * sB1 + (long long)zh * sB2;
    dst += (long long)zb * dB1 + (long long)zh * dB2;
    const int r0 = blockIdx.y * 32, c0 = blockIdx.x * 32;
    const int tx = threadIdx.x, ty = threadIdx.y;
#pragma unroll
    for (int i = 0; i < 32; i += 8)
        tile[ty + i][tx] = src[(long long)(r0 + ty + i) * sStride + (c0 + tx)];
    __syncthreads();
#pragma unroll
    for (int i = 0; i < 32; i += 8)
        dst[(long long)(c0 + ty + i) * dStride + (r0 + tx)] = tile[tx][ty + i];
}

__global__ void concat_bias(const float* __restrict__ bq, const float* __restrict__ bk,
                            const float* __restrict__ bv, float* __restrict__ dst)
{
    int i = blockIdx.x * 256 + threadIdx.x;
    int l = i / 1536, n = i - l * 1536;
    float v = (n < 512) ? bq[l * 512 + n]
             : (n < 1024 ? bk[l * 512 + (n - 512)] : bv[l * 512 + (n - 1024)]);
    dst[i] = v;
}

__global__ void mask_in(const float* __restrict__ x, const float* __restrict__ mask,
                        u16* __restrict__ out)
{
    int i4 = (blockIdx.x * 256 + threadIdx.x) * 4;
    float4 xv = *(const float4*)(x + i4);
    float m = mask[i4 >> 9];
    u16 pk[4] = {f2b(xv.x * m), f2b(xv.y * m), f2b(xv.z * m), f2b(xv.w * m)};
    uint2 p; p.x = (uint32_t)pk[0] | ((uint32_t)pk[1] << 16);
    p.y = (uint32_t)pk[2] | ((uint32_t)pk[3] << 16);
    *(uint2*)(out + i4) = p;
}

__global__ void mask_out(const u16* __restrict__ x, const float* __restrict__ mask,
                         float* __restrict__ out)
{
    int i4 = (blockIdx.x * 256 + threadIdx.x) * 4;
    uint2 p = *(const uint2*)(x + i4);
    float m = mask[i4 >> 9];
    float4 o;
    o.x = b2f((u16)(p.x & 0xffff)) * m;
    o.y = b2f((u16)(p.x >> 16)) * m;
    o.z = b2f((u16)(p.y & 0xffff)) * m;
    o.w = b2f((u16)(p.y >> 16)) * m;
    *(float4*)(out + i4) = o;
}

__global__ __launch_bounds__(256) void add_ln(
    const u16* __restrict__ x, const u16* __restrict__ y,
    const float* __restrict__ sc, const float* __restrict__ bi,
    u16* __restrict__ outx)
{
    const int wave = threadIdx.x >> 6, lane = threadIdx.x & 63;
    const long long r = (long long)blockIdx.x * 4 + wave;
    const u16* xr = x + r * C_;
    const u16* yr = y + r * C_;
    float v[8], s = 0.f;
#pragma unroll
    for (int it = 0; it < 2; ++it) {
        int j0 = it * 256 + lane * 4;
        uint2 px = *(const uint2*)(xr + j0);
        uint2 py = *(const uint2*)(yr + j0);
        v[it * 4 + 0] = b2f((u16)(px.x & 0xffff)) + b2f((u16)(py.x & 0xffff));
        v[it * 4 + 1] = b2f((u16)(px.x >> 16))    + b2f((u16)(py.x >> 16));
        v[it * 4 + 2] = b2f((u16)(px.y & 0xffff)) + b2f((u16)(py.y & 0xffff));
        v[it * 4 + 3] = b2f((u16)(px.y >> 16))    + b2f((u16)(py.y >> 16));
        s += v[it * 4 + 0] + v[it * 4 + 1] + v[it * 4 + 2] + v[it * 4 + 3];
    }
#pragma unroll
    for (int off = 32; off > 0; off >>= 1) s += __shfl_down(s, off);
    s = __shfl(s, 0);
    const float mean = s * (1.f / 512.f);
    float var = 0.f;
#pragma unroll
    for (int l = 0; l < 8; ++l) { float d = v[l] - mean; var += d * d; }
#pragma unroll
    for (int off = 32; off > 0; off >>= 1) var += __shfl_down(var, off);
    var = __shfl(var, 0);
    const float rs = rsqrtf(var * (1.f / 512.f) + 1e-6f);
    u16* orow = outx + r * C_;
#pragma unroll
    for (int it = 0; it < 2; ++it) {
        int j0 = it * 256 + lane * 4;
        float4 s4 = *(const float4*)(sc + j0);
        float4 b4 = *(const float4*)(bi + j0);
        u16 pk[4];
        pk[0] = f2b((v[it * 4 + 0] - mean) * rs * s4.x + b4.x);
        pk[1] = f2b((v[it * 4 + 1] - mean) * rs * s4.y + b4.y);
        pk[2] = f2b((v[it * 4 + 2] - mean) * rs * s4.z + b4.z);
        pk[3] = f2b((v[it * 4 + 3] - mean) * rs * s4.w + b4.w);
        uint2 p; p.x = (uint32_t)pk[0] | ((uint32_t)pk[1] << 16);
        p.y = (uint32_t)pk[2] | ((uint32_t)pk[3] << 16);
        *(uint2*)(orow + j0) = p;
    }
}

// ===========================================================================
extern "C" void kernel_launch(void* const* d_in, const int* in_sizes, int n_in,
                              void* d_out, int out_size, void* d_ws, size_t ws_size,
                              hipStream_t stream)
{
    const float* x    = (const float*)d_in[0];
    const float* mask = (const float*)d_in[1];
    const float* Wq   = (const float*)d_in[2];
    const float* bq   = (const float*)d_in[3];
    const float* Wk   = (const float*)d_in[4];
    const float* bk   = (const float*)d_in[5];
    const float* Wv   = (const float*)d_in[6];
    const float* bv   = (const float*)d_in[7];
    const float* Wo   = (const float*)d_in[8];
    const float* bo   = (const float*)d_in[9];
    const float* erk  = (const float*)d_in[10];
    const float* erv  = (const float*)d_in[11];
    const float* ln1s = (const float*)d_in[12];
    const float* ln1b = (const float*)d_in[13];
    const float* W1   = (const float*)d_in[14];
    const float* b1   = (const float*)d_in[15];
    const float* W2   = (const float*)d_in[16];
    const float* b2   = (const float*)d_in[17];
    const float* ln2s = (const float*)d_in[18];
    const float* ln2b = (const float*)d_in[19];
    float* out = (float*)d_out;
    u16* ws  = (u16*)d_ws;

    const long long CF = 512LL * 2048;
    const int M = B_ * T_;  // 6144

    // ws layout (u16 units). Total 51,234,816 u16 = 102.5 MB (<121.7 MB proven).
    u16* wqkvT   = ws;                      // [6][1536][512]
    u16* woT     = ws + 4718592;            // [6][512][512]
    u16* w1T     = ws + 6291456;            // [6][2048][512]
    u16* w2T     = ws + 12582912;           // [6][512][2048]
    float* bqkv  = (float*)(ws + 18874368); // [6][1536] f32
    u16* xb      = ws + 18892800;           // [M][512]
    u16* qkvb    = ws + 22038528;           // [M][1536]
    u16* vtb     = ws + 31475712;           // [64][64][768]; aliased as yb
    u16* attnb   = ws + 34621440;           // [M][512]
    u16* scr     = ws + 37767168;           // h1 [M][2048]
    float* bandg = (float*)(ws + 50350080); // [M][8][9] f32
    u16* yb      = vtb;

    const dim3 tb(32, 8);

    // --- one-time prologue ---
    transpose_qkvo<<<dim3(16, 16, 24), tb, 0, stream>>>(Wq, Wk, Wv, Wo, wqkvT, woT);
    transpose_f2bL<<<dim3(64, 16, 6), tb, 0, stream>>>(W1, 2048, CF, w1T, 512, 1048576);
    transpose_f2bL<<<dim3(16, 64, 6), tb, 0, stream>>>(W2, 512,  CF, w2T, 2048, 1048576);
    concat_bias<<<36, 256, 0, stream>>>(bq, bk, bv, bqkv);
    mask_in<<<(M * 512) / 1024, 256, 0, stream>>>(x, mask, xb);

    for (int l = 0; l < 6; ++l) {
        // QKV: [6144,512] @ [1536,512]^T; q *= 1/8 in epilogue
        gemm_bt<128, 3><<<dim3(48, 12, 1), 256, 0, stream>>>(
            xb, 0, 0, 512, wqkvT + (long long)l * 786432, 0, 0, 512, bqkv + l * 1536,
            qkvb, 0, 0, 1536, 512, 0.125f);
        // bandk table for this layer
        bandg_k<<<192, 256, 0, stream>>>(qkvb, erk + l * 576, bandg);
        // V^T per head: [64][768]
        transpose_b<<<dim3(2, 24, 64), tb, 0, stream>>>(
            qkvb + 1024, 768LL * 1536, 64, 1536,
            vtb, 8LL * 64 * 768, 64LL * 768, 768);
        // fused attention -> attnb
        flash_attn<<<dim3(12, 64), 256, 0, stream>>>(
            qkvb, vtb, mask, bandg, erv + l * 576, attnb);
        // O projection -> yb (=vtb, dead now)
        gemm_bt<64, 0><<<dim3(48, 8, 1), 128, 0, stream>>>(
            attnb, 0, 0, 512, woT + (long long)l * 262144, 0, 0, 512, bo + l * 512,
            yb, 0, 0, 512, 512, 0.f);
        add_ln<<<1536, 256, 0, stream>>>(xb, yb, ln1s + l * 512, ln1b + l * 512, xb);
        // FFN
        gemm_bt<128, 1><<<dim3(48, 16, 1), 256, 0, stream>>>(
            xb, 0, 0, 512, w1T + (long long)l * 1048576, 0, 0, 512, b1 + l * 2048,
            scr, 0, 0, 2048, 512, 0.f);
        gemm_bt<64, 0><<<dim3(48, 8, 1), 128, 0, stream>>>(
            scr, 0, 0, 2048, w2T + (long long)l * 1048576, 0, 0, 2048, b2 + l * 512,
            yb, 0, 0, 512, 2048, 0.f);
        add_ln<<<1536, 256, 0, stream>>>(xb, yb, ln2s + l * 512, ln2b + l * 512, xb);
    }

    mask_out<<<(M * 512) / 1024, 256, 0, stream>>>(xb, mask, out);
}